// Round 1
// baseline (774.675 us; speedup 1.0000x reference)
//
#include <hip/hip_runtime.h>
#include <cstdint>
#include <cstddef>

#define D_MODEL 1024
#define N_HEADS 16
#define D_KV    64
#define INNER   1024
#define NBATCH  4
#define SEQ     2048
#define MTOT    (NBATCH * SEQ)   // 8192

typedef _Float16 f16;
typedef __attribute__((ext_vector_type(8))) _Float16 f16x8;
typedef __attribute__((ext_vector_type(4))) _Float16 f16x4;
typedef __attribute__((ext_vector_type(4))) float    f32x4;

// ---------------------------------------------------------------- f32 -> f16
__global__ void k_cvt(const float* __restrict__ src, f16* __restrict__ dst, int n4) {
  int i = blockIdx.x * 256 + threadIdx.x;
  if (i < n4) {
    const float4 v = reinterpret_cast<const float4*>(src)[i];
    f16x4 h;
    h[0] = (f16)v.x; h[1] = (f16)v.y; h[2] = (f16)v.z; h[3] = (f16)v.w;
    reinterpret_cast<f16x4*>(dst)[i] = h;
  }
}

// ------------------------------------------------- T5 relative-pos buckets
// bucket[b][q][k], uint8.  Mirrors _relative_position_bucket (bidirectional).
__global__ void k_bucket(const int* __restrict__ pos, unsigned char* __restrict__ bkt) {
  const int k = blockIdx.x * 256 + threadIdx.x;  // grid.x = SEQ/256
  const int q = blockIdx.y;
  const int b = blockIdx.z;
  const int rel = pos[b * SEQ + k] - pos[b * SEQ + q];  // memory - context
  const int sgn = rel > 0 ? 16 : 0;
  const int a = rel < 0 ? -rel : rel;
  int bucket;
  if (a < 8) {
    bucket = a;
  } else {
    float t = logf((float)a / 8.0f);
    t = t / 2.772588722239781f;   // ln(16) (f32-rounded, matches np/jax f32 path)
    t = t * 8.0f;
    int lg = 8 + (int)t;
    bucket = lg < 15 ? lg : 15;
  }
  bkt[((size_t)(b * SEQ + q)) * SEQ + k] = (unsigned char)(sgn + bucket);
}

// ------------------------------------------------- async global->LDS (16B)
__device__ __forceinline__ void gload_lds16(const void* g, void* l) {
  __builtin_amdgcn_global_load_lds(
      (const __attribute__((address_space(1))) unsigned int*)g,
      (__attribute__((address_space(3))) unsigned int*)l,
      16, 0, 0);
}

// ------------------------------------------------- C = A * W^T  (both [*,1024] row-major, f16 in, K=1024)
// 128x128 tile, BK=64, 4 waves (2x2), mfma_f32_16x16x32_f16.  m97 structure.
template <bool OUTF32>
__device__ __forceinline__ void gemm_body(const f16* __restrict__ A,
                                          const f16* __restrict__ W,
                                          void* __restrict__ Cp) {
  __shared__ __align__(16) f16 As[128 * 64];
  __shared__ __align__(16) f16 Bs[128 * 64];
  const int t = threadIdx.x;
  const int lane = t & 63;
  const int wid = t >> 6;
  const int wr = wid >> 1;
  const int wc = wid & 1;
  const int g = lane >> 4;
  const int lr = lane & 15;
  const int m0 = blockIdx.y * 128;
  const int n0 = blockIdx.x * 128;

  f32x4 acc[4][4] = {};
  const char* Ab = (const char*)A;
  const char* Wb = (const char*)W;

  for (int kt = 0; kt < D_MODEL / 64; ++kt) {
    const int k0 = kt * 64;
    __syncthreads();  // previous iter's LDS reads done
#pragma unroll
    for (int i = 0; i < 4; ++i) {
      const int idx = i * 256 + t;      // 0..1023 16B chunks
      const int row = idx >> 3;         // 8 chunks per 128B row (BK=64 f16)
      const int cb  = (idx & 7) * 16;
      gload_lds16(Ab + ((size_t)(m0 + row) * D_MODEL + k0) * 2 + cb, (char*)As + idx * 16);
      gload_lds16(Wb + ((size_t)(n0 + row) * D_MODEL + k0) * 2 + cb, (char*)Bs + idx * 16);
    }
    asm volatile("s_waitcnt vmcnt(0)" ::: "memory");
    __syncthreads();

    f16x8 af[4][2], bf[4][2];
#pragma unroll
    for (int mi = 0; mi < 4; ++mi)
#pragma unroll
      for (int kk = 0; kk < 2; ++kk)
        af[mi][kk] = *(const f16x8*)&As[(wr * 64 + mi * 16 + lr) * 64 + kk * 32 + g * 8];
#pragma unroll
    for (int ni = 0; ni < 4; ++ni)
#pragma unroll
      for (int kk = 0; kk < 2; ++kk)
        bf[ni][kk] = *(const f16x8*)&Bs[(wc * 64 + ni * 16 + lr) * 64 + kk * 32 + g * 8];
#pragma unroll
    for (int kk = 0; kk < 2; ++kk)
#pragma unroll
      for (int mi = 0; mi < 4; ++mi)
#pragma unroll
        for (int ni = 0; ni < 4; ++ni)
          acc[mi][ni] = __builtin_amdgcn_mfma_f32_16x16x32_f16(af[mi][kk], bf[ni][kk], acc[mi][ni], 0, 0, 0);
  }

#pragma unroll
  for (int mi = 0; mi < 4; ++mi)
#pragma unroll
    for (int ni = 0; ni < 4; ++ni) {
      const int n = n0 + wc * 64 + ni * 16 + lr;
#pragma unroll
      for (int r = 0; r < 4; ++r) {
        const int m = m0 + wr * 64 + mi * 16 + g * 4 + r;  // C/D: col=lane&15, row=(lane>>4)*4+reg
        if (OUTF32)
          ((float*)Cp)[(size_t)m * INNER + n] = acc[mi][ni][r];
        else
          ((f16*)Cp)[(size_t)m * INNER + n] = (f16)acc[mi][ni][r];
      }
    }
}

__global__ __launch_bounds__(256) void k_gemm_qkv(
    const f16* __restrict__ A,
    const f16* __restrict__ Wq, const f16* __restrict__ Wk, const f16* __restrict__ Wv,
    f16* __restrict__ Cq, f16* __restrict__ Ck, f16* __restrict__ Cv) {
  const f16* W = blockIdx.z == 0 ? Wq : (blockIdx.z == 1 ? Wk : Wv);
  f16* C       = blockIdx.z == 0 ? Cq : (blockIdx.z == 1 ? Ck : Cv);
  gemm_body<false>(A, W, C);
}

__global__ __launch_bounds__(256) void k_gemm_out(
    const f16* __restrict__ A, const f16* __restrict__ W, float* __restrict__ C) {
  gemm_body<true>(A, W, C);
}

// ------------------------------------------------- flash attention, 1 wave = 16 q-rows
__global__ __launch_bounds__(256) void k_attn(
    const f16* __restrict__ Q, const f16* __restrict__ K, const f16* __restrict__ V,
    const unsigned char* __restrict__ bkt, const float* __restrict__ mask,
    const float* __restrict__ relb, f16* __restrict__ ctx) {
  __shared__ float lds_bias[32];
  __shared__ __align__(16) f16 lds_p[4][16][32];

  const int t = threadIdx.x;
  const int lane = t & 63;
  const int wid = t >> 6;
  const int bh = blockIdx.y;
  const int b = bh >> 4;
  const int h = bh & 15;
  if (t < 32) lds_bias[t] = relb[t * N_HEADS + h];
  __syncthreads();

  const int g = lane >> 4, lr = lane & 15;
  const int q0 = (blockIdx.x * 4 + wid) * 16;

  f16x8 qa[2];
#pragma unroll
  for (int kk = 0; kk < 2; ++kk)
    qa[kk] = *(const f16x8*)&Q[(size_t)(b * SEQ + q0 + lr) * INNER + h * 64 + kk * 32 + g * 8];

  f32x4 o[4] = {};
  float mrun[4], lrun[4];
#pragma unroll
  for (int r = 0; r < 4; ++r) { mrun[r] = -__builtin_inff(); lrun[r] = 0.0f; }

  const size_t kvbase = (size_t)(b * SEQ) * INNER + h * 64;
  const size_t bqbase = (size_t)(b * SEQ + q0) * SEQ;

  for (int k0 = 0; k0 < SEQ; k0 += 32) {
    f16x8 kf[2][2];
#pragma unroll
    for (int kn = 0; kn < 2; ++kn)
#pragma unroll
      for (int kk = 0; kk < 2; ++kk)
        kf[kn][kk] = *(const f16x8*)&K[kvbase + (size_t)(k0 + kn * 16 + lr) * INNER + kk * 32 + g * 8];

    f32x4 s[2];
#pragma unroll
    for (int kn = 0; kn < 2; ++kn) {
      f32x4 z = {};
      z = __builtin_amdgcn_mfma_f32_16x16x32_f16(qa[0], kf[kn][0], z, 0, 0, 0);
      z = __builtin_amdgcn_mfma_f32_16x16x32_f16(qa[1], kf[kn][1], z, 0, 0, 0);
      s[kn] = z;
    }

#pragma unroll
    for (int kn = 0; kn < 2; ++kn) {
      const int kidx = k0 + kn * 16 + lr;
      const float mterm = -1000.0f * (1.0f - mask[b * SEQ + kidx]);
#pragma unroll
      for (int r = 0; r < 4; ++r) {
        const int bb = bkt[bqbase + (size_t)(g * 4 + r) * SEQ + kidx];
        s[kn][r] += lds_bias[bb] + mterm;
      }
    }

    float mx[4];
#pragma unroll
    for (int r = 0; r < 4; ++r) mx[r] = fmaxf(s[0][r], s[1][r]);
#pragma unroll
    for (int off = 1; off < 16; off <<= 1)
#pragma unroll
      for (int r = 0; r < 4; ++r) mx[r] = fmaxf(mx[r], __shfl_xor(mx[r], off, 64));

    float mnew[4], alpha[4], ps[4];
#pragma unroll
    for (int r = 0; r < 4; ++r) {
      mnew[r] = fmaxf(mrun[r], mx[r]);
      alpha[r] = expf(mrun[r] - mnew[r]);   // first tile: exp(-inf)=0
      ps[r] = 0.0f;
    }
#pragma unroll
    for (int kn = 0; kn < 2; ++kn)
#pragma unroll
      for (int r = 0; r < 4; ++r) {
        const float p = expf(s[kn][r] - mnew[r]);
        ps[r] += p;
        lds_p[wid][g * 4 + r][kn * 16 + lr] = (f16)p;
      }
#pragma unroll
    for (int off = 1; off < 16; off <<= 1)
#pragma unroll
      for (int r = 0; r < 4; ++r) ps[r] += __shfl_xor(ps[r], off, 64);
#pragma unroll
    for (int r = 0; r < 4; ++r) {
      lrun[r] = lrun[r] * alpha[r] + ps[r];
      mrun[r] = mnew[r];
    }
#pragma unroll
    for (int dn = 0; dn < 4; ++dn)
#pragma unroll
      for (int r = 0; r < 4; ++r) o[dn][r] *= alpha[r];

    // P (16q x 32k) -> A-operand layout via per-wave LDS transpose
    const f16x8 pa = *(const f16x8*)&lds_p[wid][lr][g * 8];

#pragma unroll
    for (int dn = 0; dn < 4; ++dn) {
      f16x8 vf;
#pragma unroll
      for (int j = 0; j < 8; ++j)
        vf[j] = V[kvbase + (size_t)(k0 + g * 8 + j) * INNER + dn * 16 + lr];
      o[dn] = __builtin_amdgcn_mfma_f32_16x16x32_f16(pa, vf, o[dn], 0, 0, 0);
    }
  }

#pragma unroll
  for (int dn = 0; dn < 4; ++dn)
#pragma unroll
    for (int r = 0; r < 4; ++r) {
      const int q = q0 + g * 4 + r;
      ctx[(size_t)(b * SEQ + q) * INNER + h * 64 + dn * 16 + lr] = (f16)(o[dn][r] / lrun[r]);
    }
}

// ----------------------------------------------------------------- launch
extern "C" void kernel_launch(void* const* d_in, const int* in_sizes, int n_in,
                              void* d_out, int out_size, void* d_ws, size_t ws_size,
                              hipStream_t stream) {
  const float* hs   = (const float*)d_in[0];
  const int*   pos  = (const int*)d_in[1];
  const float* mask = (const float*)d_in[2];
  const float* wq   = (const float*)d_in[3];
  const float* wk   = (const float*)d_in[4];
  const float* wv   = (const float*)d_in[5];
  const float* wo   = (const float*)d_in[6];
  const float* relb = (const float*)d_in[7];

  char* ws = (char*)d_ws;
  const size_t SZ16 = (size_t)MTOT * INNER * 2;  // 16,777,216 B
  const size_t WSZ  = (size_t)INNER * D_MODEL * 2;  // 2,097,152 B
  f16* hs16 = (f16*)(ws);                       // reused as ctx16 after QKV GEMM
  f16* q16  = (f16*)(ws + SZ16);
  f16* k16  = (f16*)(ws + 2 * SZ16);
  f16* v16  = (f16*)(ws + 3 * SZ16);
  f16* wq16 = (f16*)(ws + 4 * SZ16);
  f16* wk16 = (f16*)(ws + 4 * SZ16 + WSZ);
  f16* wv16 = (f16*)(ws + 4 * SZ16 + 2 * WSZ);
  f16* wo16 = (f16*)(ws + 4 * SZ16 + 3 * WSZ);
  unsigned char* bkt = (unsigned char*)(ws + 4 * SZ16 + 4 * WSZ);  // 16,777,216 B
  // total ws use: 92,274,688 B

  // f32 -> f16
  k_cvt<<<(MTOT * INNER / 4 + 255) / 256, 256, 0, stream>>>(hs, hs16, MTOT * INNER / 4);
  k_cvt<<<(INNER * D_MODEL / 4 + 255) / 256, 256, 0, stream>>>(wq, wq16, INNER * D_MODEL / 4);
  k_cvt<<<(INNER * D_MODEL / 4 + 255) / 256, 256, 0, stream>>>(wk, wk16, INNER * D_MODEL / 4);
  k_cvt<<<(INNER * D_MODEL / 4 + 255) / 256, 256, 0, stream>>>(wv, wv16, INNER * D_MODEL / 4);
  k_cvt<<<(INNER * D_MODEL / 4 + 255) / 256, 256, 0, stream>>>(wo, wo16, INNER * D_MODEL / 4);

  // bucket table
  k_bucket<<<dim3(SEQ / 256, SEQ, NBATCH), 256, 0, stream>>>(pos, bkt);

  // Q/K/V projections
  k_gemm_qkv<<<dim3(INNER / 128, MTOT / 128, 3), 256, 0, stream>>>(
      hs16, wq16, wk16, wv16, q16, k16, v16);

  // attention -> ctx (f16, reuses hs16 buffer)
  k_attn<<<dim3(SEQ / 64, NBATCH * N_HEADS), 256, 0, stream>>>(
      q16, k16, v16, bkt, mask, relb, hs16);

  // output projection -> f32
  k_gemm_out<<<dim3(D_MODEL / 128, MTOT / 128), 256, 0, stream>>>(
      hs16, wo16, (float*)d_out);
}

// Round 2
// 616.388 us; speedup vs baseline: 1.2568x; 1.2568x over previous
//
#include <hip/hip_runtime.h>
#include <cstdint>
#include <cstddef>

#define D_MODEL 1024
#define N_HEADS 16
#define INNER   1024
#define NBATCH  4
#define SEQ     2048
#define MTOT    (NBATCH * SEQ)   // 8192

typedef _Float16 f16;
typedef __attribute__((ext_vector_type(8))) _Float16 f16x8;
typedef __attribute__((ext_vector_type(4))) _Float16 f16x4;
typedef __attribute__((ext_vector_type(4))) float    f32x4;

// ---------------------------------------------------------------- f32 -> f16
__global__ void k_cvt(const float* __restrict__ src, f16* __restrict__ dst, int n4) {
  int i = blockIdx.x * 256 + threadIdx.x;
  if (i < n4) {
    const float4 v = reinterpret_cast<const float4*>(src)[i];
    f16x4 h;
    h[0] = (f16)v.x; h[1] = (f16)v.y; h[2] = (f16)v.z; h[3] = (f16)v.w;
    reinterpret_cast<f16x4*>(dst)[i] = h;
  }
}

// ------------------------------------------------- T5 relative-pos buckets
__global__ void k_bucket(const int* __restrict__ pos, unsigned char* __restrict__ bkt) {
  const int k = blockIdx.x * 256 + threadIdx.x;
  const int q = blockIdx.y;
  const int b = blockIdx.z;
  const int rel = pos[b * SEQ + k] - pos[b * SEQ + q];  // memory - context
  const int sgn = rel > 0 ? 16 : 0;
  const int a = rel < 0 ? -rel : rel;
  int bucket;
  if (a < 8) {
    bucket = a;
  } else {
    float t = logf((float)a / 8.0f);
    t = t / 2.772588722239781f;   // ln(16)
    t = t * 8.0f;
    int lg = 8 + (int)t;
    bucket = lg < 15 ? lg : 15;
  }
  bkt[((size_t)(b * SEQ + q)) * SEQ + k] = (unsigned char)(sgn + bucket);
}

// ------------------------------------------------- async global->LDS (16B)
__device__ __forceinline__ void gload_lds16(const void* g, void* l) {
  __builtin_amdgcn_global_load_lds(
      (const __attribute__((address_space(1))) unsigned int*)g,
      (__attribute__((address_space(3))) unsigned int*)l,
      16, 0, 0);
}

// ------------------------------------------------- C = A * W^T  (f16 in, K=1024)
// 128x128 tile, BK=64, 4 waves (2x2), mfma_f32_16x16x32_f16.
// MODE 0: f16 row-major out; MODE 1: f32 row-major out;
// MODE 2: f16 out transposed to Vt[((b*16+h)*64+d)][s] (V for attention).
template <int MODE>
__device__ __forceinline__ void gemm_body(const f16* __restrict__ A,
                                          const f16* __restrict__ W,
                                          void* __restrict__ Cp) {
  __shared__ __align__(16) f16 As[128 * 64];
  __shared__ __align__(16) f16 Bs[128 * 64];
  const int t = threadIdx.x;
  const int lane = t & 63;
  const int wid = t >> 6;
  const int wr = wid >> 1;
  const int wc = wid & 1;
  const int g = lane >> 4;
  const int lr = lane & 15;
  const int m0 = blockIdx.y * 128;
  const int n0 = blockIdx.x * 128;

  f32x4 acc[4][4] = {};
  const char* Ab = (const char*)A;
  const char* Wb = (const char*)W;

  for (int kt = 0; kt < D_MODEL / 64; ++kt) {
    const int k0 = kt * 64;
    __syncthreads();
#pragma unroll
    for (int i = 0; i < 4; ++i) {
      const int idx = i * 256 + t;
      const int row = idx >> 3;
      const int cb  = (idx & 7) * 16;
      gload_lds16(Ab + ((size_t)(m0 + row) * D_MODEL + k0) * 2 + cb, (char*)As + idx * 16);
      gload_lds16(Wb + ((size_t)(n0 + row) * D_MODEL + k0) * 2 + cb, (char*)Bs + idx * 16);
    }
    asm volatile("s_waitcnt vmcnt(0)" ::: "memory");
    __syncthreads();

    f16x8 af[4][2], bf[4][2];
#pragma unroll
    for (int mi = 0; mi < 4; ++mi)
#pragma unroll
      for (int kk = 0; kk < 2; ++kk)
        af[mi][kk] = *(const f16x8*)&As[(wr * 64 + mi * 16 + lr) * 64 + kk * 32 + g * 8];
#pragma unroll
    for (int ni = 0; ni < 4; ++ni)
#pragma unroll
      for (int kk = 0; kk < 2; ++kk)
        bf[ni][kk] = *(const f16x8*)&Bs[(wc * 64 + ni * 16 + lr) * 64 + kk * 32 + g * 8];
#pragma unroll
    for (int kk = 0; kk < 2; ++kk)
#pragma unroll
      for (int mi = 0; mi < 4; ++mi)
#pragma unroll
        for (int ni = 0; ni < 4; ++ni)
          acc[mi][ni] = __builtin_amdgcn_mfma_f32_16x16x32_f16(af[mi][kk], bf[ni][kk], acc[mi][ni], 0, 0, 0);
  }

#pragma unroll
  for (int mi = 0; mi < 4; ++mi)
#pragma unroll
    for (int ni = 0; ni < 4; ++ni) {
      const int n = n0 + wc * 64 + ni * 16 + lr;
      if (MODE == 2) {
        // V transposed: Vt[((b*16+h)*64+d)*SEQ + s], s = token index
        const int mbase = m0 + wr * 64 + mi * 16 + g * 4;
        const int b2 = mbase >> 11, s2 = mbase & (SEQ - 1);
        const int h2 = n >> 6, d2 = n & 63;
        f16x4 w;
#pragma unroll
        for (int r = 0; r < 4; ++r) w[r] = (f16)acc[mi][ni][r];
        *(f16x4*)((f16*)Cp + ((size_t)((b2 * 16 + h2) * 64 + d2) * SEQ + s2)) = w;
      } else {
#pragma unroll
        for (int r = 0; r < 4; ++r) {
          const int m = m0 + wr * 64 + mi * 16 + g * 4 + r;
          if (MODE == 1)
            ((float*)Cp)[(size_t)m * INNER + n] = acc[mi][ni][r];
          else
            ((f16*)Cp)[(size_t)m * INNER + n] = (f16)acc[mi][ni][r];
        }
      }
    }
}

__global__ __launch_bounds__(256) void k_gemm_qkv(
    const f16* __restrict__ A,
    const f16* __restrict__ Wq, const f16* __restrict__ Wk, const f16* __restrict__ Wv,
    f16* __restrict__ Cq, f16* __restrict__ Ck, f16* __restrict__ Vt) {
  if (blockIdx.z == 0)      gemm_body<0>(A, Wq, Cq);
  else if (blockIdx.z == 1) gemm_body<0>(A, Wk, Ck);
  else                      gemm_body<2>(A, Wv, Vt);
}

__global__ __launch_bounds__(256) void k_gemm_out(
    const f16* __restrict__ A, const f16* __restrict__ W, float* __restrict__ C) {
  gemm_body<1>(A, W, C);
}

// ------------------------------------------------- flash attention
// 1 wave = 32 q-rows (two 16-col groups), KVBLK=16, swapped-operand MFMAs:
//   S = mfma16x16x32(Kfrag, Qfrag)  -> S[k=4g+r][q=lr]   (per lane: q fixed!)
//   O = mfma16x16x16(Vtfrag, Pfrag) -> O[d=4g+r][q=lr]
// P stays entirely in registers (QK D-layout k=4g+r == PV B-frag k=4g+j).
__global__ __launch_bounds__(256) void k_attn(
    const f16* __restrict__ Q, const f16* __restrict__ K, const f16* __restrict__ Vt,
    const unsigned char* __restrict__ bkt, const float* __restrict__ mask,
    const float* __restrict__ relb, f16* __restrict__ ctx) {
  __shared__ float relbL[32];
  __shared__ __align__(16) float mbL[SEQ];

  const int t = threadIdx.x, lane = t & 63, wid = t >> 6;
  const int bh = blockIdx.y, b = bh >> 4, h = bh & 15;
  const int g = lane >> 4, lr = lane & 15;

  if (t < 32) relbL[t] = relb[t * N_HEADS + h];
  for (int i = t; i < SEQ; i += 256) mbL[i] = -1000.0f * (1.0f - mask[b * SEQ + i]);
  __syncthreads();

  const int qw = blockIdx.x * 128 + wid * 32;

  f16x8 qa[2][2];
#pragma unroll
  for (int hh = 0; hh < 2; ++hh)
#pragma unroll
    for (int kk = 0; kk < 2; ++kk)
      qa[hh][kk] = *(const f16x8*)&Q[(size_t)(b * SEQ + qw + hh * 16 + lr) * INNER + h * 64 + kk * 32 + g * 8];

  f32x4 o[2][4] = {};
  float mrun[2] = {-__builtin_inff(), -__builtin_inff()};
  float lrun[2] = {0.0f, 0.0f};

  const f16* kp = K + (size_t)(b * SEQ + lr) * INNER + h * 64 + g * 8;
  const f16* vp = Vt + ((size_t)bh * 64 + lr) * SEQ + 4 * g;
  const unsigned char* bpA = bkt + (size_t)(b * SEQ + qw + lr) * SEQ + 4 * g;
  const unsigned char* bpB = bpA + (size_t)16 * SEQ;

#pragma unroll 2
  for (int k0 = 0; k0 < SEQ; k0 += 16) {
    const f16x8 kf0 = *(const f16x8*)(kp);
    const f16x8 kf1 = *(const f16x8*)(kp + 32);
    f32x4 s0 = {}, s1 = {};
    s0 = __builtin_amdgcn_mfma_f32_16x16x32_f16(kf0, qa[0][0], s0, 0, 0, 0);
    s0 = __builtin_amdgcn_mfma_f32_16x16x32_f16(kf1, qa[0][1], s0, 0, 0, 0);
    s1 = __builtin_amdgcn_mfma_f32_16x16x32_f16(kf0, qa[1][0], s1, 0, 0, 0);
    s1 = __builtin_amdgcn_mfma_f32_16x16x32_f16(kf1, qa[1][1], s1, 0, 0, 0);

    const unsigned int uA = *(const unsigned int*)(bpA + k0);
    const unsigned int uB = *(const unsigned int*)(bpB + k0);
    const float4 mb4 = *(const float4*)&mbL[k0 + 4 * g];
    const float* mbp = (const float*)&mb4;

    float sA[4], sB[4];
#pragma unroll
    for (int r = 0; r < 4; ++r) {
      sA[r] = s0[r] + relbL[(uA >> (8 * r)) & 255] + mbp[r];
      sB[r] = s1[r] + relbL[(uB >> (8 * r)) & 255] + mbp[r];
    }

    float mxA = fmaxf(fmaxf(sA[0], sA[1]), fmaxf(sA[2], sA[3]));
    float mxB = fmaxf(fmaxf(sB[0], sB[1]), fmaxf(sB[2], sB[3]));
    mxA = fmaxf(mxA, __shfl_xor(mxA, 16));
    mxA = fmaxf(mxA, __shfl_xor(mxA, 32));
    mxB = fmaxf(mxB, __shfl_xor(mxB, 16));
    mxB = fmaxf(mxB, __shfl_xor(mxB, 32));

    // defer-max (T13): rescale only when max grows past threshold 8
    if (__any((mxA > mrun[0] + 8.0f) || (mxB > mrun[1] + 8.0f))) {
      const float mnA = fmaxf(mrun[0], mxA), mnB = fmaxf(mrun[1], mxB);
      const float aA = __expf(mrun[0] - mnA), aB = __expf(mrun[1] - mnB);
      lrun[0] *= aA; lrun[1] *= aB;
#pragma unroll
      for (int dn = 0; dn < 4; ++dn)
#pragma unroll
        for (int r = 0; r < 4; ++r) { o[0][dn][r] *= aA; o[1][dn][r] *= aB; }
      mrun[0] = mnA; mrun[1] = mnB;
    }

    f16x4 pfA, pfB;
    float psA = 0.0f, psB = 0.0f;
#pragma unroll
    for (int r = 0; r < 4; ++r) {
      const float pA = __expf(sA[r] - mrun[0]);
      const float pB = __expf(sB[r] - mrun[1]);
      psA += pA; psB += pB;
      pfA[r] = (f16)pA; pfB[r] = (f16)pB;
    }
    psA += __shfl_xor(psA, 16); psA += __shfl_xor(psA, 32);
    psB += __shfl_xor(psB, 16); psB += __shfl_xor(psB, 32);
    lrun[0] += psA; lrun[1] += psB;

#pragma unroll
    for (int dn = 0; dn < 4; ++dn) {
      const f16x4 vt = *(const f16x4*)(vp + (size_t)dn * 16 * SEQ + k0);
      o[0][dn] = __builtin_amdgcn_mfma_f32_16x16x16f16(vt, pfA, o[0][dn], 0, 0, 0);
      o[1][dn] = __builtin_amdgcn_mfma_f32_16x16x16f16(vt, pfB, o[1][dn], 0, 0, 0);
    }
    kp += 16 * INNER;
  }

  const float inv[2] = {1.0f / lrun[0], 1.0f / lrun[1]};
#pragma unroll
  for (int hh = 0; hh < 2; ++hh)
#pragma unroll
    for (int dn = 0; dn < 4; ++dn) {
      f16x4 w;
#pragma unroll
      for (int r = 0; r < 4; ++r) w[r] = (f16)(o[hh][dn][r] * inv[hh]);
      *(f16x4*)&ctx[(size_t)(b * SEQ + qw + hh * 16 + lr) * INNER + h * 64 + dn * 16 + 4 * g] = w;
    }
}

// ----------------------------------------------------------------- launch
extern "C" void kernel_launch(void* const* d_in, const int* in_sizes, int n_in,
                              void* d_out, int out_size, void* d_ws, size_t ws_size,
                              hipStream_t stream) {
  const float* hs   = (const float*)d_in[0];
  const int*   pos  = (const int*)d_in[1];
  const float* mask = (const float*)d_in[2];
  const float* wq   = (const float*)d_in[3];
  const float* wk   = (const float*)d_in[4];
  const float* wv   = (const float*)d_in[5];
  const float* wo   = (const float*)d_in[6];
  const float* relb = (const float*)d_in[7];

  char* ws = (char*)d_ws;
  const size_t SZ16 = (size_t)MTOT * INNER * 2;      // 16 MiB
  const size_t WSZ  = (size_t)INNER * D_MODEL * 2;   // 2 MiB
  f16* hs16 = (f16*)(ws);                            // reused as ctx16 after QKV
  f16* q16  = (f16*)(ws + SZ16);
  f16* k16  = (f16*)(ws + 2 * SZ16);
  f16* vt16 = (f16*)(ws + 3 * SZ16);                 // V transposed [bh][d][s]
  f16* wq16 = (f16*)(ws + 4 * SZ16);
  f16* wk16 = (f16*)(ws + 4 * SZ16 + WSZ);
  f16* wv16 = (f16*)(ws + 4 * SZ16 + 2 * WSZ);
  f16* wo16 = (f16*)(ws + 4 * SZ16 + 3 * WSZ);
  unsigned char* bkt = (unsigned char*)(ws + 4 * SZ16 + 4 * WSZ);

  k_cvt<<<(MTOT * INNER / 4 + 255) / 256, 256, 0, stream>>>(hs, hs16, MTOT * INNER / 4);
  k_cvt<<<(INNER * D_MODEL / 4 + 255) / 256, 256, 0, stream>>>(wq, wq16, INNER * D_MODEL / 4);
  k_cvt<<<(INNER * D_MODEL / 4 + 255) / 256, 256, 0, stream>>>(wk, wk16, INNER * D_MODEL / 4);
  k_cvt<<<(INNER * D_MODEL / 4 + 255) / 256, 256, 0, stream>>>(wv, wv16, INNER * D_MODEL / 4);
  k_cvt<<<(INNER * D_MODEL / 4 + 255) / 256, 256, 0, stream>>>(wo, wo16, INNER * D_MODEL / 4);

  k_bucket<<<dim3(SEQ / 256, SEQ, NBATCH), 256, 0, stream>>>(pos, bkt);

  k_gemm_qkv<<<dim3(INNER / 128, MTOT / 128, 3), 256, 0, stream>>>(
      hs16, wq16, wk16, wv16, q16, k16, vt16);

  k_attn<<<dim3(SEQ / 128, NBATCH * N_HEADS), 256, 0, stream>>>(
      q16, k16, vt16, bkt, mask, relb, hs16);

  k_gemm_out<<<dim3(D_MODEL / 128, MTOT / 128), 256, 0, stream>>>(
      hs16, wo16, (float*)d_out);
}

// Round 3
// 615.171 us; speedup vs baseline: 1.2593x; 1.0020x over previous
//
#include <hip/hip_runtime.h>
#include <cstdint>
#include <cstddef>

#define D_MODEL 1024
#define N_HEADS 16
#define INNER   1024
#define NBATCH  4
#define SEQ     2048
#define MTOT    (NBATCH * SEQ)   // 8192
#define LOG2E   1.44269504088896f

typedef _Float16 f16;
typedef __attribute__((ext_vector_type(8))) _Float16 f16x8;
typedef __attribute__((ext_vector_type(4))) _Float16 f16x4;
typedef __attribute__((ext_vector_type(4))) float    f32x4;

// ---------------------------------------------------------------- f32 -> f16 (with scale)
__global__ void k_cvt(const float* __restrict__ src, f16* __restrict__ dst, int n4, float scale) {
  int i = blockIdx.x * 256 + threadIdx.x;
  if (i < n4) {
    const float4 v = reinterpret_cast<const float4*>(src)[i];
    f16x4 h;
    h[0] = (f16)(v.x * scale); h[1] = (f16)(v.y * scale);
    h[2] = (f16)(v.z * scale); h[3] = (f16)(v.w * scale);
    reinterpret_cast<f16x4*>(dst)[i] = h;
  }
}

// ------------------------------------------------- T5 relative-pos buckets
__global__ void k_bucket(const int* __restrict__ pos, unsigned char* __restrict__ bkt) {
  const int k = blockIdx.x * 256 + threadIdx.x;
  const int q = blockIdx.y;
  const int b = blockIdx.z;
  const int rel = pos[b * SEQ + k] - pos[b * SEQ + q];  // memory - context
  const int sgn = rel > 0 ? 16 : 0;
  const int a = rel < 0 ? -rel : rel;
  int bucket;
  if (a < 8) {
    bucket = a;
  } else {
    float t = logf((float)a / 8.0f);
    t = t / 2.772588722239781f;   // ln(16)
    t = t * 8.0f;
    int lg = 8 + (int)t;
    bucket = lg < 15 ? lg : 15;
  }
  bkt[((size_t)(b * SEQ + q)) * SEQ + k] = (unsigned char)(sgn + bucket);
}

// ------------------------------------------------- async global->LDS (16B)
__device__ __forceinline__ void gload_lds16(const void* g, void* l) {
  __builtin_amdgcn_global_load_lds(
      (const __attribute__((address_space(1))) unsigned int*)g,
      (__attribute__((address_space(3))) unsigned int*)l,
      16, 0, 0);
}

// ------------------------------------------------- C = A * W^T  (f16 in, K=1024)
// 128x128 tile, BK=64, 4 waves (2x2), mfma_f32_16x16x32_f16.
// MODE 0: f16 row-major out; MODE 1: f32 row-major out;
// MODE 2: f16 out transposed to Vt[((b*16+h)*64+d)][s].
template <int MODE>
__device__ __forceinline__ void gemm_body(const f16* __restrict__ A,
                                          const f16* __restrict__ W,
                                          void* __restrict__ Cp) {
  __shared__ __align__(16) f16 As[128 * 64];
  __shared__ __align__(16) f16 Bs[128 * 64];
  const int t = threadIdx.x;
  const int lane = t & 63;
  const int wid = t >> 6;
  const int wr = wid >> 1;
  const int wc = wid & 1;
  const int g = lane >> 4;
  const int lr = lane & 15;
  const int m0 = blockIdx.y * 128;
  const int n0 = blockIdx.x * 128;

  f32x4 acc[4][4] = {};
  const char* Ab = (const char*)A;
  const char* Wb = (const char*)W;

  for (int kt = 0; kt < D_MODEL / 64; ++kt) {
    const int k0 = kt * 64;
    __syncthreads();
#pragma unroll
    for (int i = 0; i < 4; ++i) {
      const int idx = i * 256 + t;
      const int row = idx >> 3;
      const int cb  = (idx & 7) * 16;
      gload_lds16(Ab + ((size_t)(m0 + row) * D_MODEL + k0) * 2 + cb, (char*)As + idx * 16);
      gload_lds16(Wb + ((size_t)(n0 + row) * D_MODEL + k0) * 2 + cb, (char*)Bs + idx * 16);
    }
    asm volatile("s_waitcnt vmcnt(0)" ::: "memory");
    __syncthreads();

    f16x8 af[4][2], bf[4][2];
#pragma unroll
    for (int mi = 0; mi < 4; ++mi)
#pragma unroll
      for (int kk = 0; kk < 2; ++kk)
        af[mi][kk] = *(const f16x8*)&As[(wr * 64 + mi * 16 + lr) * 64 + kk * 32 + g * 8];
#pragma unroll
    for (int ni = 0; ni < 4; ++ni)
#pragma unroll
      for (int kk = 0; kk < 2; ++kk)
        bf[ni][kk] = *(const f16x8*)&Bs[(wc * 64 + ni * 16 + lr) * 64 + kk * 32 + g * 8];
#pragma unroll
    for (int kk = 0; kk < 2; ++kk)
#pragma unroll
      for (int mi = 0; mi < 4; ++mi)
#pragma unroll
        for (int ni = 0; ni < 4; ++ni)
          acc[mi][ni] = __builtin_amdgcn_mfma_f32_16x16x32_f16(af[mi][kk], bf[ni][kk], acc[mi][ni], 0, 0, 0);
  }

#pragma unroll
  for (int mi = 0; mi < 4; ++mi)
#pragma unroll
    for (int ni = 0; ni < 4; ++ni) {
      const int n = n0 + wc * 64 + ni * 16 + lr;
      if (MODE == 2) {
        const int mbase = m0 + wr * 64 + mi * 16 + g * 4;
        const int b2 = mbase >> 11, s2 = mbase & (SEQ - 1);
        const int h2 = n >> 6, d2 = n & 63;
        f16x4 w;
#pragma unroll
        for (int r = 0; r < 4; ++r) w[r] = (f16)acc[mi][ni][r];
        *(f16x4*)((f16*)Cp + ((size_t)((b2 * 16 + h2) * 64 + d2) * SEQ + s2)) = w;
      } else {
#pragma unroll
        for (int r = 0; r < 4; ++r) {
          const int m = m0 + wr * 64 + mi * 16 + g * 4 + r;
          if (MODE == 1)
            ((float*)Cp)[(size_t)m * INNER + n] = acc[mi][ni][r];
          else
            ((f16*)Cp)[(size_t)m * INNER + n] = (f16)acc[mi][ni][r];
        }
      }
    }
}

__global__ __launch_bounds__(256) void k_gemm_qkv(
    const f16* __restrict__ A,
    const f16* __restrict__ Wq, const f16* __restrict__ Wk, const f16* __restrict__ Wv,
    f16* __restrict__ Cq, f16* __restrict__ Ck, f16* __restrict__ Vt) {
  if (blockIdx.z == 0)      gemm_body<0>(A, Wq, Cq);
  else if (blockIdx.z == 1) gemm_body<0>(A, Wk, Ck);
  else                      gemm_body<2>(A, Wv, Vt);
}

__global__ __launch_bounds__(256) void k_gemm_out(
    const f16* __restrict__ A, const f16* __restrict__ W, float* __restrict__ C) {
  gemm_body<1>(A, W, C);
}

// ------------------------------------------------- flash attention
// 1 wave = 32 q-rows, KVBLK=32, swapped-operand MFMAs, P in registers.
// Scores are in the log2 domain (wq pre-scaled by log2e; relb/mask scaled here)
// so softmax uses raw v_exp_f32 (exp2).  K register-double-buffered (T14);
// issue order buckets -> V -> next-K so softmax waits don't drain K prefetch.
__global__ __launch_bounds__(256) void k_attn(
    const f16* __restrict__ Q, const f16* __restrict__ K, const f16* __restrict__ Vt,
    const unsigned char* __restrict__ bkt, const float* __restrict__ mask,
    const float* __restrict__ relb, f16* __restrict__ ctx) {
  __shared__ float relbL[32];
  __shared__ __align__(16) float mbL[SEQ];

  // XCD-aware remap: 1024 blocks = 8 xcd-chunks x 128; all 16 q-chunks of a
  // (b,h) land on one XCD -> its K/V (512KB x 8 bh = 4MB) stays in that L2.
  const int nb = (int)blockIdx.x;
  const int v = (nb & 7) * 128 + (nb >> 3);
  const int bh = v >> 4, qc = v & 15;
  const int b = bh >> 4, h = bh & 15;

  const int t = threadIdx.x, lane = t & 63, wid = t >> 6;
  const int g = lane >> 4, lr = lane & 15;

  if (t < 32) relbL[t] = relb[t * N_HEADS + h] * LOG2E;
  for (int i = t; i < SEQ; i += 256) mbL[i] = -1442.695041f * (1.0f - mask[b * SEQ + i]);
  __syncthreads();

  const int qw = qc * 128 + wid * 32;

  f16x8 qa[2][2];
#pragma unroll
  for (int hh = 0; hh < 2; ++hh)
#pragma unroll
    for (int kk = 0; kk < 2; ++kk)
      qa[hh][kk] = *(const f16x8*)&Q[(size_t)(b * SEQ + qw + hh * 16 + lr) * INNER + h * 64 + kk * 32 + g * 8];

  f32x4 o[2][4] = {};
  float mrun[2] = {-__builtin_inff(), -__builtin_inff()};
  float lrun[2] = {0.0f, 0.0f};

  const f16* kp = K + (size_t)(b * SEQ + lr) * INNER + h * 64 + g * 8;
  const f16* vp = Vt + ((size_t)bh * 64 + lr) * SEQ + 4 * g;
  const unsigned char* bpA = bkt + (size_t)(b * SEQ + qw + lr) * SEQ + 4 * g;
  const unsigned char* bpB = bpA + (size_t)16 * SEQ;

  f16x8 kb[2][2][2];  // [buf][sub][d-half]
#pragma unroll
  for (int s = 0; s < 2; ++s) {
    kb[0][s][0] = *(const f16x8*)(kp + (size_t)(s * 16) * INNER);
    kb[0][s][1] = *(const f16x8*)(kp + (size_t)(s * 16) * INNER + 32);
  }

#pragma unroll 2
  for (int k0 = 0; k0 < SEQ; k0 += 32) {
    const int p = (k0 >> 5) & 1;

    // ---- issue loads early: buckets first (oldest -> waited first), V, then next-K
    unsigned int u[2][2];
    u[0][0] = *(const unsigned int*)(bpA + k0);
    u[1][0] = *(const unsigned int*)(bpA + k0 + 16);
    u[0][1] = *(const unsigned int*)(bpB + k0);
    u[1][1] = *(const unsigned int*)(bpB + k0 + 16);
    float4 mb[2];
    mb[0] = *(const float4*)&mbL[k0 + 4 * g];
    mb[1] = *(const float4*)&mbL[k0 + 16 + 4 * g];

    f16x4 vt[2][4];
#pragma unroll
    for (int s = 0; s < 2; ++s)
#pragma unroll
      for (int dn = 0; dn < 4; ++dn)
        vt[s][dn] = *(const f16x4*)(vp + (size_t)dn * 16 * SEQ + k0 + s * 16);

    // prefetch next K tile (last iter overreads into adjacent ws buffer — safe)
#pragma unroll
    for (int s = 0; s < 2; ++s) {
      const f16* kpn = kp + (size_t)(k0 + 32 + s * 16) * INNER;
      kb[p ^ 1][s][0] = *(const f16x8*)(kpn);
      kb[p ^ 1][s][1] = *(const f16x8*)(kpn + 32);
    }

    // ---- QK^T from the resident buffer
    f32x4 sg[2][2];  // [hh][sub]
#pragma unroll
    for (int hh = 0; hh < 2; ++hh)
#pragma unroll
      for (int s = 0; s < 2; ++s) {
        f32x4 z = {};
        z = __builtin_amdgcn_mfma_f32_16x16x32_f16(kb[p][s][0], qa[hh][0], z, 0, 0, 0);
        z = __builtin_amdgcn_mfma_f32_16x16x32_f16(kb[p][s][1], qa[hh][1], z, 0, 0, 0);
        sg[hh][s] = z;
      }

    float sA[2][4], sB[2][4];
#pragma unroll
    for (int s = 0; s < 2; ++s)
#pragma unroll
      for (int r = 0; r < 4; ++r) {
        const float bb = ((const float*)&mb[s])[r];
        sA[s][r] = sg[0][s][r] + relbL[(u[s][0] >> (8 * r)) & 255] + bb;
        sB[s][r] = sg[1][s][r] + relbL[(u[s][1] >> (8 * r)) & 255] + bb;
      }

    float mxA = fmaxf(fmaxf(fmaxf(sA[0][0], sA[0][1]), fmaxf(sA[0][2], sA[0][3])),
                      fmaxf(fmaxf(sA[1][0], sA[1][1]), fmaxf(sA[1][2], sA[1][3])));
    float mxB = fmaxf(fmaxf(fmaxf(sB[0][0], sB[0][1]), fmaxf(sB[0][2], sB[0][3])),
                      fmaxf(fmaxf(sB[1][0], sB[1][1]), fmaxf(sB[1][2], sB[1][3])));
    mxA = fmaxf(mxA, __shfl_xor(mxA, 16));
    mxA = fmaxf(mxA, __shfl_xor(mxA, 32));
    mxB = fmaxf(mxB, __shfl_xor(mxB, 16));
    mxB = fmaxf(mxB, __shfl_xor(mxB, 32));

    // defer-max (T13), threshold 8 in nat-log = 11.54 in log2 domain
    if (__any((mxA > mrun[0] + 11.5415603f) || (mxB > mrun[1] + 11.5415603f))) {
      const float mnA = fmaxf(mrun[0], mxA), mnB = fmaxf(mrun[1], mxB);
      const float aA = __builtin_amdgcn_exp2f(mrun[0] - mnA);
      const float aB = __builtin_amdgcn_exp2f(mrun[1] - mnB);
      lrun[0] *= aA; lrun[1] *= aB;
#pragma unroll
      for (int dn = 0; dn < 4; ++dn)
#pragma unroll
        for (int r = 0; r < 4; ++r) { o[0][dn][r] *= aA; o[1][dn][r] *= aB; }
      mrun[0] = mnA; mrun[1] = mnB;
    }

    f16x4 pfA[2], pfB[2];
    float psA = 0.0f, psB = 0.0f;
#pragma unroll
    for (int s = 0; s < 2; ++s)
#pragma unroll
      for (int r = 0; r < 4; ++r) {
        const float pA = __builtin_amdgcn_exp2f(sA[s][r] - mrun[0]);
        const float pB = __builtin_amdgcn_exp2f(sB[s][r] - mrun[1]);
        psA += pA; psB += pB;
        pfA[s][r] = (f16)pA; pfB[s][r] = (f16)pB;
      }
    psA += __shfl_xor(psA, 16); psA += __shfl_xor(psA, 32);
    psB += __shfl_xor(psB, 16); psB += __shfl_xor(psB, 32);
    lrun[0] += psA; lrun[1] += psB;

#pragma unroll
    for (int s = 0; s < 2; ++s)
#pragma unroll
      for (int dn = 0; dn < 4; ++dn) {
        o[0][dn] = __builtin_amdgcn_mfma_f32_16x16x16f16(vt[s][dn], pfA[s], o[0][dn], 0, 0, 0);
        o[1][dn] = __builtin_amdgcn_mfma_f32_16x16x16f16(vt[s][dn], pfB[s], o[1][dn], 0, 0, 0);
      }
  }

  const float invA = 1.0f / lrun[0], invB = 1.0f / lrun[1];
#pragma unroll
  for (int dn = 0; dn < 4; ++dn) {
    f16x4 wA, wB;
#pragma unroll
    for (int r = 0; r < 4; ++r) {
      wA[r] = (f16)(o[0][dn][r] * invA);
      wB[r] = (f16)(o[1][dn][r] * invB);
    }
    *(f16x4*)&ctx[(size_t)(b * SEQ + qw + lr) * INNER + h * 64 + dn * 16 + 4 * g] = wA;
    *(f16x4*)&ctx[(size_t)(b * SEQ + qw + 16 + lr) * INNER + h * 64 + dn * 16 + 4 * g] = wB;
  }
}

// ----------------------------------------------------------------- launch
extern "C" void kernel_launch(void* const* d_in, const int* in_sizes, int n_in,
                              void* d_out, int out_size, void* d_ws, size_t ws_size,
                              hipStream_t stream) {
  const float* hs   = (const float*)d_in[0];
  const int*   pos  = (const int*)d_in[1];
  const float* mask = (const float*)d_in[2];
  const float* wq   = (const float*)d_in[3];
  const float* wk   = (const float*)d_in[4];
  const float* wv   = (const float*)d_in[5];
  const float* wo   = (const float*)d_in[6];
  const float* relb = (const float*)d_in[7];

  char* ws = (char*)d_ws;
  const size_t SZ16 = (size_t)MTOT * INNER * 2;      // 16 MiB
  const size_t WSZ  = (size_t)INNER * D_MODEL * 2;   // 2 MiB
  f16* hs16 = (f16*)(ws);                            // reused as ctx16 after QKV
  f16* q16  = (f16*)(ws + SZ16);
  f16* k16  = (f16*)(ws + 2 * SZ16);
  f16* vt16 = (f16*)(ws + 3 * SZ16);                 // V transposed [bh][d][s]
  f16* wq16 = (f16*)(ws + 4 * SZ16);
  f16* wk16 = (f16*)(ws + 4 * SZ16 + WSZ);
  f16* wv16 = (f16*)(ws + 4 * SZ16 + 2 * WSZ);
  f16* wo16 = (f16*)(ws + 4 * SZ16 + 3 * WSZ);
  unsigned char* bkt = (unsigned char*)(ws + 4 * SZ16 + 4 * WSZ);

  // wq is pre-scaled by log2(e) so QK^T scores land in the log2 domain.
  k_cvt<<<(MTOT * INNER / 4 + 255) / 256, 256, 0, stream>>>(hs, hs16, MTOT * INNER / 4, 1.0f);
  k_cvt<<<(INNER * D_MODEL / 4 + 255) / 256, 256, 0, stream>>>(wq, wq16, INNER * D_MODEL / 4, LOG2E);
  k_cvt<<<(INNER * D_MODEL / 4 + 255) / 256, 256, 0, stream>>>(wk, wk16, INNER * D_MODEL / 4, 1.0f);
  k_cvt<<<(INNER * D_MODEL / 4 + 255) / 256, 256, 0, stream>>>(wv, wv16, INNER * D_MODEL / 4, 1.0f);
  k_cvt<<<(INNER * D_MODEL / 4 + 255) / 256, 256, 0, stream>>>(wo, wo16, INNER * D_MODEL / 4, 1.0f);

  k_bucket<<<dim3(SEQ / 256, SEQ, NBATCH), 256, 0, stream>>>(pos, bkt);

  k_gemm_qkv<<<dim3(INNER / 128, MTOT / 128, 3), 256, 0, stream>>>(
      hs16, wq16, wk16, wv16, q16, k16, vt16);

  k_attn<<<dim3(1024), 256, 0, stream>>>(
      q16, k16, vt16, bkt, mask, relb, hs16);

  k_gemm_out<<<dim3(D_MODEL / 128, MTOT / 128), 256, 0, stream>>>(
      hs16, wo16, (float*)d_out);
}

// Round 6
// 336.870 us; speedup vs baseline: 2.2996x; 1.8261x over previous
//
#include <hip/hip_runtime.h>
#include <cstdint>
#include <cstddef>

#define D_MODEL 1024
#define N_HEADS 16
#define INNER   1024
#define NBATCH  4
#define SEQ     2048
#define MTOT    (NBATCH * SEQ)   // 8192
#define LOG2E   1.44269504088896f

typedef _Float16 f16;
typedef __attribute__((ext_vector_type(8))) _Float16 f16x8;
typedef __attribute__((ext_vector_type(4))) _Float16 f16x4;
typedef __attribute__((ext_vector_type(4))) float    f32x4;

// ---------------------------------------------------------------- f32 -> f16 (with scale)
__global__ void k_cvt(const float* __restrict__ src, f16* __restrict__ dst, int n4, float scale) {
  int i = blockIdx.x * 256 + threadIdx.x;
  if (i < n4) {
    const float4 v = reinterpret_cast<const float4*>(src)[i];
    f16x4 h;
    h[0] = (f16)(v.x * scale); h[1] = (f16)(v.y * scale);
    h[2] = (f16)(v.z * scale); h[3] = (f16)(v.w * scale);
    reinterpret_cast<f16x4*>(dst)[i] = h;
  }
}

// ------------------------------------------------- T5 relative-pos buckets, packed
// bkt4[((b*512 + k/4) * SEQ) + q] = uchar4 of buckets for keys 4*(k/4)..+3.
__global__ void k_bucket4(const int* __restrict__ pos, unsigned int* __restrict__ bkt4) {
  const int q  = blockIdx.x * 256 + threadIdx.x;
  const int kq = blockIdx.y;      // 0..511
  const int b  = blockIdx.z;
  const int pq = pos[b * SEQ + q];
  unsigned int out = 0;
#pragma unroll
  for (int r = 0; r < 4; ++r) {
    const int k = kq * 4 + r;
    const int rel = pos[b * SEQ + k] - pq;  // memory - context
    const int sgn = rel > 0 ? 16 : 0;
    const int a = rel < 0 ? -rel : rel;
    int bucket;
    if (a < 8) {
      bucket = a;
    } else {
      float t = logf((float)a / 8.0f);
      t = t / 2.772588722239781f;   // ln(16)
      t = t * 8.0f;
      int lg = 8 + (int)t;
      bucket = lg < 15 ? lg : 15;
    }
    out |= (unsigned int)(sgn + bucket) << (8 * r);
  }
  bkt4[((size_t)(b * 512 + kq)) * SEQ + q] = out;
}

// ------------------------------------------------- async global->LDS (16B)
__device__ __forceinline__ void gload_lds16(const void* g, void* l) {
  __builtin_amdgcn_global_load_lds(
      (const __attribute__((address_space(1))) unsigned int*)g,
      (__attribute__((address_space(3))) unsigned int*)l,
      16, 0, 0);
}

// NOTE: round-4/5 used inline-asm v_permlane32_swap with two "+v" operands
// initialized from the SAME value; regalloc may alias them to one VGPR ->
// self-swap -> reduce drops x[lane]. Reverted to known-good DS shuffle.

// ------------------------------------------------- C = A * W^T  (f16 in, K=1024)
// 128x128 tile, BK=64, 4 waves (2x2), mfma_f32_16x16x32_f16.
// MODE 0: f16 row-major out; MODE 1: f32 row-major out;
// MODE 2: f16 out transposed to Vt[((b*16+h)*64+d)][s].
template <int MODE>
__device__ __forceinline__ void gemm_body(const f16* __restrict__ A,
                                          const f16* __restrict__ W,
                                          void* __restrict__ Cp) {
  __shared__ __align__(16) f16 As[128 * 64];
  __shared__ __align__(16) f16 Bs[128 * 64];
  const int t = threadIdx.x;
  const int lane = t & 63;
  const int wid = t >> 6;
  const int wr = wid >> 1;
  const int wc = wid & 1;
  const int g = lane >> 4;
  const int lr = lane & 15;
  const int m0 = blockIdx.y * 128;
  const int n0 = blockIdx.x * 128;

  f32x4 acc[4][4] = {};
  const char* Ab = (const char*)A;
  const char* Wb = (const char*)W;

  for (int kt = 0; kt < D_MODEL / 64; ++kt) {
    const int k0 = kt * 64;
    __syncthreads();
#pragma unroll
    for (int i = 0; i < 4; ++i) {
      const int idx = i * 256 + t;
      const int row = idx >> 3;
      const int cb  = (idx & 7) * 16;
      gload_lds16(Ab + ((size_t)(m0 + row) * D_MODEL + k0) * 2 + cb, (char*)As + idx * 16);
      gload_lds16(Wb + ((size_t)(n0 + row) * D_MODEL + k0) * 2 + cb, (char*)Bs + idx * 16);
    }
    asm volatile("s_waitcnt vmcnt(0)" ::: "memory");
    __syncthreads();

    f16x8 af[4][2], bf[4][2];
#pragma unroll
    for (int mi = 0; mi < 4; ++mi)
#pragma unroll
      for (int kk = 0; kk < 2; ++kk)
        af[mi][kk] = *(const f16x8*)&As[(wr * 64 + mi * 16 + lr) * 64 + kk * 32 + g * 8];
#pragma unroll
    for (int ni = 0; ni < 4; ++ni)
#pragma unroll
      for (int kk = 0; kk < 2; ++kk)
        bf[ni][kk] = *(const f16x8*)&Bs[(wc * 64 + ni * 16 + lr) * 64 + kk * 32 + g * 8];
#pragma unroll
    for (int kk = 0; kk < 2; ++kk)
#pragma unroll
      for (int mi = 0; mi < 4; ++mi)
#pragma unroll
        for (int ni = 0; ni < 4; ++ni)
          acc[mi][ni] = __builtin_amdgcn_mfma_f32_16x16x32_f16(af[mi][kk], bf[ni][kk], acc[mi][ni], 0, 0, 0);
  }

#pragma unroll
  for (int mi = 0; mi < 4; ++mi)
#pragma unroll
    for (int ni = 0; ni < 4; ++ni) {
      const int n = n0 + wc * 64 + ni * 16 + lr;
      if (MODE == 2) {
        const int mbase = m0 + wr * 64 + mi * 16 + g * 4;
        const int b2 = mbase >> 11, s2 = mbase & (SEQ - 1);
        const int h2 = n >> 6, d2 = n & 63;
        f16x4 w;
#pragma unroll
        for (int r = 0; r < 4; ++r) w[r] = (f16)acc[mi][ni][r];
        *(f16x4*)((f16*)Cp + ((size_t)((b2 * 16 + h2) * 64 + d2) * SEQ + s2)) = w;
      } else {
#pragma unroll
        for (int r = 0; r < 4; ++r) {
          const int m = m0 + wr * 64 + mi * 16 + g * 4 + r;
          if (MODE == 1)
            ((float*)Cp)[(size_t)m * INNER + n] = acc[mi][ni][r];
          else
            ((f16*)Cp)[(size_t)m * INNER + n] = (f16)acc[mi][ni][r];
        }
      }
    }
}

__global__ __launch_bounds__(256) void k_gemm_qkv(
    const f16* __restrict__ A,
    const f16* __restrict__ Wq, const f16* __restrict__ Wk, const f16* __restrict__ Wv,
    f16* __restrict__ Cq, f16* __restrict__ Ck, f16* __restrict__ Vt) {
  if (blockIdx.z == 0)      gemm_body<0>(A, Wq, Cq);
  else if (blockIdx.z == 1) gemm_body<0>(A, Wk, Ck);
  else                      gemm_body<2>(A, Wv, Vt);
}

__global__ __launch_bounds__(256) void k_gemm_out(
    const f16* __restrict__ A, const f16* __restrict__ W, float* __restrict__ C) {
  gemm_body<1>(A, W, C);
}

// ------------------------------------------------- flash attention
// Block = 4 waves, one (b,h), 128 q-rows; wave = 32 q.  KVBLK=32.
// K/V staged in LDS (coalesced global_load_lds, XOR-swizzled at 16B
// granularity = staging chunk size), double-buffered.
// Swapped-operand MFMAs keep P in registers; scores in log2 domain.
__global__ __launch_bounds__(256) void k_attn(
    const f16* __restrict__ Q, const f16* __restrict__ K, const f16* __restrict__ Vt,
    const unsigned int* __restrict__ bkt4, const float* __restrict__ mask,
    const float* __restrict__ relb, f16* __restrict__ ctx) {
  __shared__ float relbL[32];
  __shared__ __align__(16) float mbL[SEQ];
  __shared__ __align__(16) f16 Ks[2][32 * 64];   // [k][d], 128B rows, swz bits 4-6
  __shared__ __align__(16) f16 Vs[2][64 * 32];   // [d][k], 64B rows,  swz bits 4-5

  // XCD-aware remap: all 16 q-chunks of one (b,h) on one XCD.
  const int nb = (int)blockIdx.x;
  const int v = (nb & 7) * 128 + (nb >> 3);
  const int bh = v >> 4, qc = v & 15;
  const int b = bh >> 4, h = bh & 15;

  const int t = threadIdx.x, lane = t & 63, wid = t >> 6;
  const int g = lane >> 4, lr = lane & 15;

  if (t < 32) relbL[t] = relb[t * N_HEADS + h] * LOG2E;
  for (int i = t; i < SEQ; i += 256) mbL[i] = -1442.695041f * (1.0f - mask[b * SEQ + i]);

  // staging: 256 threads cover one 4KB K-tile + 4KB V-tile, 1 x 16B chunk each.
  // Swizzle applied on the GLOBAL source (m173); XOR bits >= chunk alignment (16B).
  const char* Kg = (const char*)K + ((size_t)(b * SEQ) * INNER + h * 64) * 2;
  const char* Vg = (const char*)Vt + ((size_t)bh * 64) * SEQ * 2;
  const int krow = t >> 3, kch = t & 7;
  const int ksrc = (kch * 16) ^ ((krow & 7) << 4);   // bits 4-6, 16B chunks: consistent
  const int vrow = t >> 2, vch = t & 3;
  const int vsrc = (vch * 16) ^ ((vrow & 3) << 4);   // bits 4-5 only (16B granularity)

  const int qw = qc * 128 + wid * 32;

  f16x8 qa[2][2];
#pragma unroll
  for (int hh = 0; hh < 2; ++hh)
#pragma unroll
    for (int kk = 0; kk < 2; ++kk)
      qa[hh][kk] = *(const f16x8*)&Q[(size_t)(b * SEQ + qw + hh * 16 + lr) * INNER + h * 64 + kk * 32 + g * 8];

  f32x4 o[2][4] = {};
  float mrun[2] = {-__builtin_inff(), -__builtin_inff()};
  float lrun[2] = {0.0f, 0.0f};

  const unsigned int* bq4 = bkt4 + (size_t)b * 512 * SEQ + qw + lr;

  // prologue: stage tile 0
  gload_lds16(Kg + ((size_t)(0 + krow) * INNER) * 2 + ksrc, (char*)&Ks[0][0] + t * 16);
  gload_lds16(Vg + ((size_t)vrow * SEQ + 0) * 2 + vsrc,     (char*)&Vs[0][0] + t * 16);
  asm volatile("s_waitcnt vmcnt(0)" ::: "memory");
  __syncthreads();

  for (int k0 = 0; k0 < SEQ; k0 += 32) {
    const int buf = (k0 >> 5) & 1;

    // bucket loads first (in-order vmcnt retirement: consuming u won't drain stage)
    unsigned int u[2][2];
    const int kqb = k0 >> 2;
#pragma unroll
    for (int s = 0; s < 2; ++s)
#pragma unroll
      for (int hh = 0; hh < 2; ++hh)
        u[s][hh] = bq4[(size_t)(kqb + s * 4 + g) * SEQ + hh * 16];

    // prefetch next tile into the other buffer
    const int k0n = (k0 + 32 < SEQ) ? (k0 + 32) : 0;
    gload_lds16(Kg + ((size_t)(k0n + krow) * INNER) * 2 + ksrc, (char*)&Ks[buf ^ 1][0] + t * 16);
    gload_lds16(Vg + ((size_t)vrow * SEQ + k0n) * 2 + vsrc,     (char*)&Vs[buf ^ 1][0] + t * 16);

    // ---- K fragments from LDS, QK^T
    const char* kb_ = (const char*)&Ks[buf][0];
    f16x8 kf[2][2];
#pragma unroll
    for (int s = 0; s < 2; ++s)
#pragma unroll
      for (int half = 0; half < 2; ++half)
        kf[s][half] = *(const f16x8*)(kb_ + (s * 16 + lr) * 128 + ((half * 64 + g * 16) ^ ((lr & 7) << 4)));

    f32x4 sg[2][2];  // [hh][s]
#pragma unroll
    for (int hh = 0; hh < 2; ++hh)
#pragma unroll
      for (int s = 0; s < 2; ++s) {
        f32x4 z = {};
        z = __builtin_amdgcn_mfma_f32_16x16x32_f16(kf[s][0], qa[hh][0], z, 0, 0, 0);
        z = __builtin_amdgcn_mfma_f32_16x16x32_f16(kf[s][1], qa[hh][1], z, 0, 0, 0);
        sg[hh][s] = z;
      }

    float4 mb[2];
    mb[0] = *(const float4*)&mbL[k0 + 4 * g];
    mb[1] = *(const float4*)&mbL[k0 + 16 + 4 * g];

    float sA[2][4], sB[2][4];
#pragma unroll
    for (int s = 0; s < 2; ++s)
#pragma unroll
      for (int r = 0; r < 4; ++r) {
        const float bb = ((const float*)&mb[s])[r];
        sA[s][r] = sg[0][s][r] + relbL[(u[s][0] >> (8 * r)) & 255] + bb;
        sB[s][r] = sg[1][s][r] + relbL[(u[s][1] >> (8 * r)) & 255] + bb;
      }

    float mxA = fmaxf(fmaxf(fmaxf(sA[0][0], sA[0][1]), fmaxf(sA[0][2], sA[0][3])),
                      fmaxf(fmaxf(sA[1][0], sA[1][1]), fmaxf(sA[1][2], sA[1][3])));
    float mxB = fmaxf(fmaxf(fmaxf(sB[0][0], sB[0][1]), fmaxf(sB[0][2], sB[0][3])),
                      fmaxf(fmaxf(sB[1][0], sB[1][1]), fmaxf(sB[1][2], sB[1][3])));
    mxA = fmaxf(mxA, __shfl_xor(mxA, 16));
    mxB = fmaxf(mxB, __shfl_xor(mxB, 16));
    mxA = fmaxf(mxA, __shfl_xor(mxA, 32));
    mxB = fmaxf(mxB, __shfl_xor(mxB, 32));

    // defer-max (T13): threshold 8 nats = 11.54 in log2 domain
    if (__any((mxA > mrun[0] + 11.5415603f) || (mxB > mrun[1] + 11.5415603f))) {
      const float mnA = fmaxf(mrun[0], mxA), mnB = fmaxf(mrun[1], mxB);
      const float aA = __builtin_amdgcn_exp2f(mrun[0] - mnA);
      const float aB = __builtin_amdgcn_exp2f(mrun[1] - mnB);
      lrun[0] *= aA; lrun[1] *= aB;
#pragma unroll
      for (int dn = 0; dn < 4; ++dn)
#pragma unroll
        for (int r = 0; r < 4; ++r) { o[0][dn][r] *= aA; o[1][dn][r] *= aB; }
      mrun[0] = mnA; mrun[1] = mnB;
    }

    f16x4 pfA[2], pfB[2];
    float psA = 0.0f, psB = 0.0f;
#pragma unroll
    for (int s = 0; s < 2; ++s)
#pragma unroll
      for (int r = 0; r < 4; ++r) {
        const float pA = __builtin_amdgcn_exp2f(sA[s][r] - mrun[0]);
        const float pB = __builtin_amdgcn_exp2f(sB[s][r] - mrun[1]);
        psA += pA; psB += pB;
        pfA[s][r] = (f16)pA; pfB[s][r] = (f16)pB;
      }
    psA += __shfl_xor(psA, 16);
    psB += __shfl_xor(psB, 16);
    psA += __shfl_xor(psA, 32);
    psB += __shfl_xor(psB, 32);
    lrun[0] += psA; lrun[1] += psB;

    // ---- V fragments from LDS, PV  (swz bits 4-5: an 8B read stays in one 16B chunk)
    const char* vb_ = (const char*)&Vs[buf][0];
#pragma unroll
    for (int s = 0; s < 2; ++s)
#pragma unroll
      for (int dn = 0; dn < 4; ++dn) {
        const f16x4 vt = *(const f16x4*)(vb_ + (dn * 16 + lr) * 64 + ((s * 32 + g * 8) ^ ((lr & 3) << 4)));
        o[0][dn] = __builtin_amdgcn_mfma_f32_16x16x16f16(vt, pfA[s], o[0][dn], 0, 0, 0);
        o[1][dn] = __builtin_amdgcn_mfma_f32_16x16x16f16(vt, pfB[s], o[1][dn], 0, 0, 0);
      }

    asm volatile("s_waitcnt vmcnt(0)" ::: "memory");  // next tile staged
    __syncthreads();
  }

  const float invA = 1.0f / lrun[0], invB = 1.0f / lrun[1];
#pragma unroll
  for (int dn = 0; dn < 4; ++dn) {
    f16x4 wA, wB;
#pragma unroll
    for (int r = 0; r < 4; ++r) {
      wA[r] = (f16)(o[0][dn][r] * invA);
      wB[r] = (f16)(o[1][dn][r] * invB);
    }
    *(f16x4*)&ctx[(size_t)(b * SEQ + qw + lr) * INNER + h * 64 + dn * 16 + 4 * g] = wA;
    *(f16x4*)&ctx[(size_t)(b * SEQ + qw + 16 + lr) * INNER + h * 64 + dn * 16 + 4 * g] = wB;
  }
}

// ----------------------------------------------------------------- launch
extern "C" void kernel_launch(void* const* d_in, const int* in_sizes, int n_in,
                              void* d_out, int out_size, void* d_ws, size_t ws_size,
                              hipStream_t stream) {
  const float* hs   = (const float*)d_in[0];
  const int*   pos  = (const int*)d_in[1];
  const float* mask = (const float*)d_in[2];
  const float* wq   = (const float*)d_in[3];
  const float* wk   = (const float*)d_in[4];
  const float* wv   = (const float*)d_in[5];
  const float* wo   = (const float*)d_in[6];
  const float* relb = (const float*)d_in[7];

  char* ws = (char*)d_ws;
  const size_t SZ16 = (size_t)MTOT * INNER * 2;      // 16 MiB
  const size_t WSZ  = (size_t)INNER * D_MODEL * 2;   // 2 MiB
  f16* hs16 = (f16*)(ws);                            // reused as ctx16 after QKV
  f16* q16  = (f16*)(ws + SZ16);
  f16* k16  = (f16*)(ws + 2 * SZ16);
  f16* vt16 = (f16*)(ws + 3 * SZ16);                 // V transposed [bh][d][s]
  f16* wq16 = (f16*)(ws + 4 * SZ16);
  f16* wk16 = (f16*)(ws + 4 * SZ16 + WSZ);
  f16* wv16 = (f16*)(ws + 4 * SZ16 + 2 * WSZ);
  f16* wo16 = (f16*)(ws + 4 * SZ16 + 3 * WSZ);
  unsigned int* bkt4 = (unsigned int*)(ws + 4 * SZ16 + 4 * WSZ);  // 16 MiB

  // wq pre-scaled by log2(e): QK^T scores land in the log2 domain.
  k_cvt<<<(MTOT * INNER / 4 + 255) / 256, 256, 0, stream>>>(hs, hs16, MTOT * INNER / 4, 1.0f);
  k_cvt<<<(INNER * D_MODEL / 4 + 255) / 256, 256, 0, stream>>>(wq, wq16, INNER * D_MODEL / 4, LOG2E);
  k_cvt<<<(INNER * D_MODEL / 4 + 255) / 256, 256, 0, stream>>>(wk, wk16, INNER * D_MODEL / 4, 1.0f);
  k_cvt<<<(INNER * D_MODEL / 4 + 255) / 256, 256, 0, stream>>>(wv, wv16, INNER * D_MODEL / 4, 1.0f);
  k_cvt<<<(INNER * D_MODEL / 4 + 255) / 256, 256, 0, stream>>>(wo, wo16, INNER * D_MODEL / 4, 1.0f);

  k_bucket4<<<dim3(SEQ / 256, SEQ / 4, NBATCH), 256, 0, stream>>>(pos, bkt4);

  k_gemm_qkv<<<dim3(INNER / 128, MTOT / 128, 3), 256, 0, stream>>>(
      hs16, wq16, wk16, wv16, q16, k16, vt16);

  k_attn<<<dim3(1024), 256, 0, stream>>>(
      q16, k16, vt16, bkt4, mask, relb, hs16);

  k_gemm_out<<<dim3(D_MODEL / 128, MTOT / 128), 256, 0, stream>>>(
      hs16, wo16, (float*)d_out);
}

// Round 7
// 329.578 us; speedup vs baseline: 2.3505x; 1.0221x over previous
//
#include <hip/hip_runtime.h>
#include <cstdint>
#include <cstddef>

#define D_MODEL 1024
#define N_HEADS 16
#define INNER   1024
#define NBATCH  4
#define SEQ     2048
#define MTOT    (NBATCH * SEQ)   // 8192
#define LOG2E   1.44269504088896f
#define BSTRIDE 4352             // biasG per-head stride (>= 4097, mult of 256)

typedef _Float16 f16;
typedef __attribute__((ext_vector_type(8))) _Float16 f16x8;
typedef __attribute__((ext_vector_type(4))) _Float16 f16x4;
typedef __attribute__((ext_vector_type(4))) float    f32x4;

// ---------------------------------------------------------------- f32 -> f16 (with scale)
__global__ void k_cvt(const float* __restrict__ src, f16* __restrict__ dst, int n4, float scale) {
  int i = blockIdx.x * 256 + threadIdx.x;
  if (i < n4) {
    const float4 v = reinterpret_cast<const float4*>(src)[i];
    f16x4 h;
    h[0] = (f16)(v.x * scale); h[1] = (f16)(v.y * scale);
    h[2] = (f16)(v.z * scale); h[3] = (f16)(v.w * scale);
    reinterpret_cast<f16x4*>(dst)[i] = h;
  }
}

// ------------------------------------------------- T5 relative bias as 1-D delta table
// positions = arange(B*S) -> rel_pos(q,k) = k - q for every batch.
// biasG[h][2048 + delta] = relb[bucket(delta)][h] * LOG2E   (log2-domain softmax)
__global__ void k_bias(const float* __restrict__ relb, float* __restrict__ biasG) {
  const int i = blockIdx.x * 256 + threadIdx.x;  // 0..4351
  const int h = blockIdx.y;
  const int d = i - 2048;
  const int sgn = d > 0 ? 16 : 0;
  const int a = d < 0 ? -d : d;
  int bucket;
  if (a < 8) {
    bucket = a;
  } else {
    float t = logf((float)a / 8.0f);
    t = t / 2.772588722239781f;   // ln(16)
    t = t * 8.0f;
    int lg = 8 + (int)t;
    bucket = lg < 15 ? lg : 15;
  }
  biasG[h * BSTRIDE + i] = relb[(sgn + bucket) * N_HEADS + h] * LOG2E;
}

// ------------------------------------------------- async global->LDS (16B)
__device__ __forceinline__ void gload_lds16(const void* g, void* l) {
  __builtin_amdgcn_global_load_lds(
      (const __attribute__((address_space(1))) unsigned int*)g,
      (__attribute__((address_space(3))) unsigned int*)l,
      16, 0, 0);
}

// ------------------------------------------------- C = A * W^T  (f16 in, K=1024)
// 128x128 tile, BK=64, 4 waves (2x2), mfma_f32_16x16x32_f16.
// MODE 0: f16 row-major out; MODE 1: f32 row-major out;
// MODE 2: f16 out transposed to Vt[((b*16+h)*64+d)][s].
template <int MODE>
__device__ __forceinline__ void gemm_body(const f16* __restrict__ A,
                                          const f16* __restrict__ W,
                                          void* __restrict__ Cp) {
  __shared__ __align__(16) f16 As[128 * 64];
  __shared__ __align__(16) f16 Bs[128 * 64];
  const int t = threadIdx.x;
  const int lane = t & 63;
  const int wid = t >> 6;
  const int wr = wid >> 1;
  const int wc = wid & 1;
  const int g = lane >> 4;
  const int lr = lane & 15;
  const int m0 = blockIdx.y * 128;
  const int n0 = blockIdx.x * 128;

  f32x4 acc[4][4] = {};
  const char* Ab = (const char*)A;
  const char* Wb = (const char*)W;

  for (int kt = 0; kt < D_MODEL / 64; ++kt) {
    const int k0 = kt * 64;
    __syncthreads();
#pragma unroll
    for (int i = 0; i < 4; ++i) {
      const int idx = i * 256 + t;
      const int row = idx >> 3;
      const int cb  = (idx & 7) * 16;
      gload_lds16(Ab + ((size_t)(m0 + row) * D_MODEL + k0) * 2 + cb, (char*)As + idx * 16);
      gload_lds16(Wb + ((size_t)(n0 + row) * D_MODEL + k0) * 2 + cb, (char*)Bs + idx * 16);
    }
    asm volatile("s_waitcnt vmcnt(0)" ::: "memory");
    __syncthreads();

    f16x8 af[4][2], bf[4][2];
#pragma unroll
    for (int mi = 0; mi < 4; ++mi)
#pragma unroll
      for (int kk = 0; kk < 2; ++kk)
        af[mi][kk] = *(const f16x8*)&As[(wr * 64 + mi * 16 + lr) * 64 + kk * 32 + g * 8];
#pragma unroll
    for (int ni = 0; ni < 4; ++ni)
#pragma unroll
      for (int kk = 0; kk < 2; ++kk)
        bf[ni][kk] = *(const f16x8*)&Bs[(wc * 64 + ni * 16 + lr) * 64 + kk * 32 + g * 8];
#pragma unroll
    for (int kk = 0; kk < 2; ++kk)
#pragma unroll
      for (int mi = 0; mi < 4; ++mi)
#pragma unroll
        for (int ni = 0; ni < 4; ++ni)
          acc[mi][ni] = __builtin_amdgcn_mfma_f32_16x16x32_f16(af[mi][kk], bf[ni][kk], acc[mi][ni], 0, 0, 0);
  }

#pragma unroll
  for (int mi = 0; mi < 4; ++mi)
#pragma unroll
    for (int ni = 0; ni < 4; ++ni) {
      const int n = n0 + wc * 64 + ni * 16 + lr;
      if (MODE == 2) {
        const int mbase = m0 + wr * 64 + mi * 16 + g * 4;
        const int b2 = mbase >> 11, s2 = mbase & (SEQ - 1);
        const int h2 = n >> 6, d2 = n & 63;
        f16x4 w;
#pragma unroll
        for (int r = 0; r < 4; ++r) w[r] = (f16)acc[mi][ni][r];
        *(f16x4*)((f16*)Cp + ((size_t)((b2 * 16 + h2) * 64 + d2) * SEQ + s2)) = w;
      } else {
#pragma unroll
        for (int r = 0; r < 4; ++r) {
          const int m = m0 + wr * 64 + mi * 16 + g * 4 + r;
          if (MODE == 1)
            ((float*)Cp)[(size_t)m * INNER + n] = acc[mi][ni][r];
          else
            ((f16*)Cp)[(size_t)m * INNER + n] = (f16)acc[mi][ni][r];
        }
      }
    }
}

__global__ __launch_bounds__(256) void k_gemm_qkv(
    const f16* __restrict__ A,
    const f16* __restrict__ Wq, const f16* __restrict__ Wk, const f16* __restrict__ Wv,
    f16* __restrict__ Cq, f16* __restrict__ Ck, f16* __restrict__ Vt) {
  if (blockIdx.z == 0)      gemm_body<0>(A, Wq, Cq);
  else if (blockIdx.z == 1) gemm_body<0>(A, Wk, Ck);
  else                      gemm_body<2>(A, Wv, Vt);
}

__global__ __launch_bounds__(256) void k_gemm_out(
    const f16* __restrict__ A, const f16* __restrict__ W, float* __restrict__ C) {
  gemm_body<1>(A, W, C);
}

// ------------------------------------------------- flash attention
// Block = 4 waves, one (b,h), 128 q-rows; wave = 32 q.  KVBLK=32.
// K/V staged in LDS (global_load_lds, 16B-granular XOR swizzle), double-buffered.
// Relative bias via per-block LDS window of the 1-D delta table (conflict-free
// gathers).  Swapped-operand MFMAs keep P in registers; log2-domain softmax.
__global__ __launch_bounds__(256) void k_attn(
    const f16* __restrict__ Q, const f16* __restrict__ K, const f16* __restrict__ Vt,
    const float* __restrict__ biasG, const float* __restrict__ mask,
    f16* __restrict__ ctx) {
  __shared__ __align__(16) float biasT[2176];
  __shared__ __align__(16) float mbL[SEQ];
  __shared__ __align__(16) f16 Ks[2][32 * 64];   // [k][d], 128B rows, swz bits 4-6
  __shared__ __align__(16) f16 Vs[2][64 * 32];   // [d][k], 64B rows,  swz bits 4-5

  // XCD-aware remap: all 16 q-chunks of one (b,h) on one XCD.
  const int nb = (int)blockIdx.x;
  const int v = (nb & 7) * 128 + (nb >> 3);
  const int bh = v >> 4, qc = v & 15;
  const int b = bh >> 4, h = bh & 15;

  const int t = threadIdx.x, lane = t & 63, wid = t >> 6;
  const int g = lane >> 4, lr = lane & 15;
  const int qb = qc * 128;

  // bias window: biasT[j] = biasG[h][2048 + (j - 127 - qb)], j in [0,2176)
  {
    const float* bgh = biasG + (size_t)h * BSTRIDE + (1921 - qb);
    for (int i = t; i < 2176; i += 256) biasT[i] = bgh[i];
  }
  for (int i = t; i < SEQ; i += 256) mbL[i] = -1442.695041f * (1.0f - mask[b * SEQ + i]);

  // staging: 256 threads cover one 4KB K-tile + 4KB V-tile, 1 x 16B chunk each.
  // Swizzle applied on the GLOBAL source; XOR bits >= chunk alignment (16B).
  const char* Kg = (const char*)K + ((size_t)(b * SEQ) * INNER + h * 64) * 2;
  const char* Vg = (const char*)Vt + ((size_t)bh * 64) * SEQ * 2;
  const int krow = t >> 3, kch = t & 7;
  const int ksrc = (kch * 16) ^ ((krow & 7) << 4);
  const int vrow = t >> 2, vch = t & 3;
  const int vsrc = (vch * 16) ^ ((vrow & 3) << 4);

  const int qw = qb + wid * 32;

  f16x8 qa[2][2];
#pragma unroll
  for (int hh = 0; hh < 2; ++hh)
#pragma unroll
    for (int kk = 0; kk < 2; ++kk)
      qa[hh][kk] = *(const f16x8*)&Q[(size_t)(b * SEQ + qw + hh * 16 + lr) * INNER + h * 64 + kk * 32 + g * 8];

  f32x4 o[2][4] = {};
  float mrun[2] = {-__builtin_inff(), -__builtin_inff()};
  float lrun[2] = {0.0f, 0.0f};

  // per-lane bias index base: j = k0 + s*16 - hh*16 + 4g + r + jbase
  const int jbase = 127 + 4 * g - wid * 32 - lr;

  // prologue: stage tile 0
  gload_lds16(Kg + ((size_t)(0 + krow) * INNER) * 2 + ksrc, (char*)&Ks[0][0] + t * 16);
  gload_lds16(Vg + ((size_t)vrow * SEQ + 0) * 2 + vsrc,     (char*)&Vs[0][0] + t * 16);
  asm volatile("s_waitcnt vmcnt(0)" ::: "memory");
  __syncthreads();

  for (int k0 = 0; k0 < SEQ; k0 += 32) {
    const int buf = (k0 >> 5) & 1;

    // prefetch next tile into the other buffer
    const int k0n = (k0 + 32 < SEQ) ? (k0 + 32) : 0;
    gload_lds16(Kg + ((size_t)(k0n + krow) * INNER) * 2 + ksrc, (char*)&Ks[buf ^ 1][0] + t * 16);
    gload_lds16(Vg + ((size_t)vrow * SEQ + k0n) * 2 + vsrc,     (char*)&Vs[buf ^ 1][0] + t * 16);

    // ---- K and V fragments from LDS (V early: latency hides under QK MFMA)
    const char* kb_ = (const char*)&Ks[buf][0];
    f16x8 kf[2][2];
#pragma unroll
    for (int s = 0; s < 2; ++s)
#pragma unroll
      for (int half = 0; half < 2; ++half)
        kf[s][half] = *(const f16x8*)(kb_ + (s * 16 + lr) * 128 + ((half * 64 + g * 16) ^ ((lr & 7) << 4)));

    const char* vb_ = (const char*)&Vs[buf][0];
    f16x4 vt[2][4];
#pragma unroll
    for (int s = 0; s < 2; ++s)
#pragma unroll
      for (int dn = 0; dn < 4; ++dn)
        vt[s][dn] = *(const f16x4*)(vb_ + (dn * 16 + lr) * 64 + ((s * 32 + g * 8) ^ ((lr & 3) << 4)));

    f32x4 sg[2][2];  // [hh][s]
#pragma unroll
    for (int hh = 0; hh < 2; ++hh)
#pragma unroll
      for (int s = 0; s < 2; ++s) {
        f32x4 z = {};
        z = __builtin_amdgcn_mfma_f32_16x16x32_f16(kf[s][0], qa[hh][0], z, 0, 0, 0);
        z = __builtin_amdgcn_mfma_f32_16x16x32_f16(kf[s][1], qa[hh][1], z, 0, 0, 0);
        sg[hh][s] = z;
      }

    float4 mb[2];
    mb[0] = *(const float4*)&mbL[k0 + 4 * g];
    mb[1] = *(const float4*)&mbL[k0 + 16 + 4 * g];

    float sA[2][4], sB[2][4];
#pragma unroll
    for (int s = 0; s < 2; ++s) {
      const int jA = k0 + s * 16 + jbase;        // hh = 0
#pragma unroll
      for (int r = 0; r < 4; ++r) {
        const float bb = ((const float*)&mb[s])[r];
        sA[s][r] = sg[0][s][r] + biasT[jA + r] + bb;
        sB[s][r] = sg[1][s][r] + biasT[jA - 16 + r] + bb;   // hh = 1
      }
    }

    float mxA = fmaxf(fmaxf(fmaxf(sA[0][0], sA[0][1]), fmaxf(sA[0][2], sA[0][3])),
                      fmaxf(fmaxf(sA[1][0], sA[1][1]), fmaxf(sA[1][2], sA[1][3])));
    float mxB = fmaxf(fmaxf(fmaxf(sB[0][0], sB[0][1]), fmaxf(sB[0][2], sB[0][3])),
                      fmaxf(fmaxf(sB[1][0], sB[1][1]), fmaxf(sB[1][2], sB[1][3])));
    mxA = fmaxf(mxA, __shfl_xor(mxA, 16));
    mxB = fmaxf(mxB, __shfl_xor(mxB, 16));
    mxA = fmaxf(mxA, __shfl_xor(mxA, 32));
    mxB = fmaxf(mxB, __shfl_xor(mxB, 32));

    // defer-max (T13): threshold 8 nats = 11.54 in log2 domain
    if (__any((mxA > mrun[0] + 11.5415603f) || (mxB > mrun[1] + 11.5415603f))) {
      const float mnA = fmaxf(mrun[0], mxA), mnB = fmaxf(mrun[1], mxB);
      const float aA = __builtin_amdgcn_exp2f(mrun[0] - mnA);
      const float aB = __builtin_amdgcn_exp2f(mrun[1] - mnB);
      lrun[0] *= aA; lrun[1] *= aB;
#pragma unroll
      for (int dn = 0; dn < 4; ++dn)
#pragma unroll
        for (int r = 0; r < 4; ++r) { o[0][dn][r] *= aA; o[1][dn][r] *= aB; }
      mrun[0] = mnA; mrun[1] = mnB;
    }

    f16x4 pfA[2], pfB[2];
    float psA = 0.0f, psB = 0.0f;
#pragma unroll
    for (int s = 0; s < 2; ++s)
#pragma unroll
      for (int r = 0; r < 4; ++r) {
        const float pA = __builtin_amdgcn_exp2f(sA[s][r] - mrun[0]);
        const float pB = __builtin_amdgcn_exp2f(sB[s][r] - mrun[1]);
        psA += pA; psB += pB;
        pfA[s][r] = (f16)pA; pfB[s][r] = (f16)pB;
      }

    // ---- PV first; the l-sum shuffles below have no consumer until loop end,
    // so their DS latency overlaps the MFMAs.
#pragma unroll
    for (int s = 0; s < 2; ++s)
#pragma unroll
      for (int dn = 0; dn < 4; ++dn) {
        o[0][dn] = __builtin_amdgcn_mfma_f32_16x16x16f16(vt[s][dn], pfA[s], o[0][dn], 0, 0, 0);
        o[1][dn] = __builtin_amdgcn_mfma_f32_16x16x16f16(vt[s][dn], pfB[s], o[1][dn], 0, 0, 0);
      }

    psA += __shfl_xor(psA, 16);
    psB += __shfl_xor(psB, 16);
    psA += __shfl_xor(psA, 32);
    psB += __shfl_xor(psB, 32);
    lrun[0] += psA; lrun[1] += psB;

    asm volatile("s_waitcnt vmcnt(0)" ::: "memory");  // next tile staged
    __syncthreads();
  }

  const float invA = 1.0f / lrun[0], invB = 1.0f / lrun[1];
#pragma unroll
  for (int dn = 0; dn < 4; ++dn) {
    f16x4 wA, wB;
#pragma unroll
    for (int r = 0; r < 4; ++r) {
      wA[r] = (f16)(o[0][dn][r] * invA);
      wB[r] = (f16)(o[1][dn][r] * invB);
    }
    *(f16x4*)&ctx[(size_t)(b * SEQ + qw + lr) * INNER + h * 64 + dn * 16 + 4 * g] = wA;
    *(f16x4*)&ctx[(size_t)(b * SEQ + qw + 16 + lr) * INNER + h * 64 + dn * 16 + 4 * g] = wB;
  }
}

// ----------------------------------------------------------------- launch
extern "C" void kernel_launch(void* const* d_in, const int* in_sizes, int n_in,
                              void* d_out, int out_size, void* d_ws, size_t ws_size,
                              hipStream_t stream) {
  const float* hs   = (const float*)d_in[0];
  const float* mask = (const float*)d_in[2];
  const float* wq   = (const float*)d_in[3];
  const float* wk   = (const float*)d_in[4];
  const float* wv   = (const float*)d_in[5];
  const float* wo   = (const float*)d_in[6];
  const float* relb = (const float*)d_in[7];

  char* ws = (char*)d_ws;
  const size_t SZ16 = (size_t)MTOT * INNER * 2;      // 16 MiB
  const size_t WSZ  = (size_t)INNER * D_MODEL * 2;   // 2 MiB
  f16* hs16 = (f16*)(ws);                            // reused as ctx16 after QKV
  f16* q16  = (f16*)(ws + SZ16);
  f16* k16  = (f16*)(ws + 2 * SZ16);
  f16* vt16 = (f16*)(ws + 3 * SZ16);                 // V transposed [bh][d][s]
  f16* wq16 = (f16*)(ws + 4 * SZ16);
  f16* wk16 = (f16*)(ws + 4 * SZ16 + WSZ);
  f16* wv16 = (f16*)(ws + 4 * SZ16 + 2 * WSZ);
  f16* wo16 = (f16*)(ws + 4 * SZ16 + 3 * WSZ);
  float* biasG = (float*)(ws + 4 * SZ16 + 4 * WSZ);  // 16*4352*4 = 278,528 B

  // wq pre-scaled by log2(e): QK^T scores land in the log2 domain.
  k_cvt<<<(MTOT * INNER / 4 + 255) / 256, 256, 0, stream>>>(hs, hs16, MTOT * INNER / 4, 1.0f);
  k_cvt<<<(INNER * D_MODEL / 4 + 255) / 256, 256, 0, stream>>>(wq, wq16, INNER * D_MODEL / 4, LOG2E);
  k_cvt<<<(INNER * D_MODEL / 4 + 255) / 256, 256, 0, stream>>>(wk, wk16, INNER * D_MODEL / 4, 1.0f);
  k_cvt<<<(INNER * D_MODEL / 4 + 255) / 256, 256, 0, stream>>>(wv, wv16, INNER * D_MODEL / 4, 1.0f);
  k_cvt<<<(INNER * D_MODEL / 4 + 255) / 256, 256, 0, stream>>>(wo, wo16, INNER * D_MODEL / 4, 1.0f);

  k_bias<<<dim3(BSTRIDE / 256, N_HEADS), 256, 0, stream>>>(relb, biasG);

  k_gemm_qkv<<<dim3(INNER / 128, MTOT / 128, 3), 256, 0, stream>>>(
      hs16, wq16, wk16, wv16, q16, k16, vt16);

  k_attn<<<dim3(1024), 256, 0, stream>>>(
      q16, k16, vt16, biasG, mask, hs16);

  k_gemm_out<<<dim3(D_MODEL / 128, MTOT / 128), 256, 0, stream>>>(
      hs16, wo16, (float*)d_out);
}

// Round 8
// 297.447 us; speedup vs baseline: 2.6044x; 1.1080x over previous
//
#include <hip/hip_runtime.h>
#include <cstdint>
#include <cstddef>

#define D_MODEL 1024
#define N_HEADS 16
#define INNER   1024
#define NBATCH  4
#define SEQ     2048
#define MTOT    (NBATCH * SEQ)   // 8192
#define LOG2E   1.44269504088896f
#define BSTRIDE 4352             // biasG per-head stride (>= 4097, mult of 256)

typedef _Float16 f16;
typedef __attribute__((ext_vector_type(8))) _Float16 f16x8;
typedef __attribute__((ext_vector_type(4))) _Float16 f16x4;
typedef __attribute__((ext_vector_type(4))) float    f32x4;

// ---------------------------------------------------------------- f32 -> f16 (with scale)
__global__ void k_cvt(const float* __restrict__ src, f16* __restrict__ dst, int n4, float scale) {
  int i = blockIdx.x * 256 + threadIdx.x;
  if (i < n4) {
    const float4 v = reinterpret_cast<const float4*>(src)[i];
    f16x4 h;
    h[0] = (f16)(v.x * scale); h[1] = (f16)(v.y * scale);
    h[2] = (f16)(v.z * scale); h[3] = (f16)(v.w * scale);
    reinterpret_cast<f16x4*>(dst)[i] = h;
  }
}

// ------------------------------------------------- T5 relative bias as 1-D delta table
// positions = arange(B*S) -> rel_pos(q,k) = k - q for every batch.
// biasG[h][2048 + delta] = relb[bucket(delta)][h] * LOG2E   (log2-domain softmax)
__global__ void k_bias(const float* __restrict__ relb, float* __restrict__ biasG) {
  const int i = blockIdx.x * 256 + threadIdx.x;  // 0..4351
  const int h = blockIdx.y;
  const int d = i - 2048;
  const int sgn = d > 0 ? 16 : 0;
  const int a = d < 0 ? -d : d;
  int bucket;
  if (a < 8) {
    bucket = a;
  } else {
    float t = logf((float)a / 8.0f);
    t = t / 2.772588722239781f;   // ln(16)
    t = t * 8.0f;
    int lg = 8 + (int)t;
    bucket = lg < 15 ? lg : 15;
  }
  biasG[h * BSTRIDE + i] = relb[(sgn + bucket) * N_HEADS + h] * LOG2E;
}

// ------------------------------------------------- async global->LDS (16B)
__device__ __forceinline__ void gload_lds16(const void* g, void* l) {
  __builtin_amdgcn_global_load_lds(
      (const __attribute__((address_space(1))) unsigned int*)g,
      (__attribute__((address_space(3))) unsigned int*)l,
      16, 0, 0);
}

// ------------------------------------------------- C = A * W^T  (f16 in, K=1024)
// 128x128 tile, BK=64, 4 waves (2x2), mfma_f32_16x16x32_f16.
// MODE 0: f16 row-major out; MODE 1: f32 row-major out;
// MODE 2: f16 out transposed to Vt[((b*16+h)*64+d)][s].
template <int MODE>
__device__ __forceinline__ void gemm_body(const f16* __restrict__ A,
                                          const f16* __restrict__ W,
                                          void* __restrict__ Cp) {
  __shared__ __align__(16) f16 As[128 * 64];
  __shared__ __align__(16) f16 Bs[128 * 64];
  const int t = threadIdx.x;
  const int lane = t & 63;
  const int wid = t >> 6;
  const int wr = wid >> 1;
  const int wc = wid & 1;
  const int g = lane >> 4;
  const int lr = lane & 15;
  const int m0 = blockIdx.y * 128;
  const int n0 = blockIdx.x * 128;

  f32x4 acc[4][4] = {};
  const char* Ab = (const char*)A;
  const char* Wb = (const char*)W;

  for (int kt = 0; kt < D_MODEL / 64; ++kt) {
    const int k0 = kt * 64;
    __syncthreads();
#pragma unroll
    for (int i = 0; i < 4; ++i) {
      const int idx = i * 256 + t;
      const int row = idx >> 3;
      const int cb  = (idx & 7) * 16;
      gload_lds16(Ab + ((size_t)(m0 + row) * D_MODEL + k0) * 2 + cb, (char*)As + idx * 16);
      gload_lds16(Wb + ((size_t)(n0 + row) * D_MODEL + k0) * 2 + cb, (char*)Bs + idx * 16);
    }
    asm volatile("s_waitcnt vmcnt(0)" ::: "memory");
    __syncthreads();

    f16x8 af[4][2], bf[4][2];
#pragma unroll
    for (int mi = 0; mi < 4; ++mi)
#pragma unroll
      for (int kk = 0; kk < 2; ++kk)
        af[mi][kk] = *(const f16x8*)&As[(wr * 64 + mi * 16 + lr) * 64 + kk * 32 + g * 8];
#pragma unroll
    for (int ni = 0; ni < 4; ++ni)
#pragma unroll
      for (int kk = 0; kk < 2; ++kk)
        bf[ni][kk] = *(const f16x8*)&Bs[(wc * 64 + ni * 16 + lr) * 64 + kk * 32 + g * 8];
#pragma unroll
    for (int kk = 0; kk < 2; ++kk)
#pragma unroll
      for (int mi = 0; mi < 4; ++mi)
#pragma unroll
        for (int ni = 0; ni < 4; ++ni)
          acc[mi][ni] = __builtin_amdgcn_mfma_f32_16x16x32_f16(af[mi][kk], bf[ni][kk], acc[mi][ni], 0, 0, 0);
  }

#pragma unroll
  for (int mi = 0; mi < 4; ++mi)
#pragma unroll
    for (int ni = 0; ni < 4; ++ni) {
      const int n = n0 + wc * 64 + ni * 16 + lr;
      if (MODE == 2) {
        const int mbase = m0 + wr * 64 + mi * 16 + g * 4;
        const int b2 = mbase >> 11, s2 = mbase & (SEQ - 1);
        const int h2 = n >> 6, d2 = n & 63;
        f16x4 w;
#pragma unroll
        for (int r = 0; r < 4; ++r) w[r] = (f16)acc[mi][ni][r];
        *(f16x4*)((f16*)Cp + ((size_t)((b2 * 16 + h2) * 64 + d2) * SEQ + s2)) = w;
      } else {
#pragma unroll
        for (int r = 0; r < 4; ++r) {
          const int m = m0 + wr * 64 + mi * 16 + g * 4 + r;
          if (MODE == 1)
            ((float*)Cp)[(size_t)m * INNER + n] = acc[mi][ni][r];
          else
            ((f16*)Cp)[(size_t)m * INNER + n] = (f16)acc[mi][ni][r];
        }
      }
    }
}

__global__ __launch_bounds__(256) void k_gemm_qkv(
    const f16* __restrict__ A,
    const f16* __restrict__ Wq, const f16* __restrict__ Wk, const f16* __restrict__ Wv,
    f16* __restrict__ Cq, f16* __restrict__ Ck, f16* __restrict__ Vt) {
  if (blockIdx.z == 0)      gemm_body<0>(A, Wq, Cq);
  else if (blockIdx.z == 1) gemm_body<0>(A, Wk, Ck);
  else                      gemm_body<2>(A, Wv, Vt);
}

__global__ __launch_bounds__(256) void k_gemm_out(
    const f16* __restrict__ A, const f16* __restrict__ W, float* __restrict__ C) {
  gemm_body<1>(A, W, C);
}

// ------------------------------------------------- flash attention
// Block = 4 waves, one (b,h), 128 q-rows; wave = 32 q.  KVBLK=32.
// K/V staged in LDS (global_load_lds, 16B-granular XOR swizzle), double-buffered.
// Bias+mask enter as the QK MFMA C-operand.  Lane-local defer-max: NO cross-lane
// ops in the steady-state iteration; l-sum reduced once in the epilogue.
__global__ __launch_bounds__(256) void k_attn(
    const f16* __restrict__ Q, const f16* __restrict__ K, const f16* __restrict__ Vt,
    const float* __restrict__ biasG, const float* __restrict__ mask,
    f16* __restrict__ ctx) {
  __shared__ __align__(16) float biasT[2176];
  __shared__ __align__(16) float mbL[SEQ];
  __shared__ __align__(16) f16 Ks[2][32 * 64];   // [k][d], 128B rows, swz bits 4-6
  __shared__ __align__(16) f16 Vs[2][64 * 32];   // [d][k], 64B rows,  swz bits 4-5

  // XCD-aware remap: all 16 q-chunks of one (b,h) on one XCD.
  const int nb = (int)blockIdx.x;
  const int v = (nb & 7) * 128 + (nb >> 3);
  const int bh = v >> 4, qc = v & 15;
  const int b = bh >> 4, h = bh & 15;

  const int t = threadIdx.x, lane = t & 63, wid = t >> 6;
  const int g = lane >> 4, lr = lane & 15;
  const int qb = qc * 128;

  // bias window: biasT[j] = biasG[h][2048 + (j - 127 - qb)], j in [0,2176)
  {
    const float* bgh = biasG + (size_t)h * BSTRIDE + (1921 - qb);
    for (int i = t; i < 2176; i += 256) biasT[i] = bgh[i];
  }
  for (int i = t; i < SEQ; i += 256) mbL[i] = -1442.695041f * (1.0f - mask[b * SEQ + i]);

  // staging: 256 threads cover one 4KB K-tile + 4KB V-tile, 1 x 16B chunk each.
  const char* Kg = (const char*)K + ((size_t)(b * SEQ) * INNER + h * 64) * 2;
  const char* Vg = (const char*)Vt + ((size_t)bh * 64) * SEQ * 2;
  const int krow = t >> 3, kch = t & 7;
  const int ksrc = (kch * 16) ^ ((krow & 7) << 4);
  const int vrow = t >> 2, vch = t & 3;
  const int vsrc = (vch * 16) ^ ((vrow & 3) << 4);

  const int qw = qb + wid * 32;

  f16x8 qa[2][2];
#pragma unroll
  for (int hh = 0; hh < 2; ++hh)
#pragma unroll
    for (int kk = 0; kk < 2; ++kk)
      qa[hh][kk] = *(const f16x8*)&Q[(size_t)(b * SEQ + qw + hh * 16 + lr) * INNER + h * 64 + kk * 32 + g * 8];

  f32x4 o[2][4] = {};
  float mrun[2] = {-__builtin_inff(), -__builtin_inff()};  // wave max at last rescale
  float lsum[2] = {0.0f, 0.0f};                            // per-lane partial sums

  // per-lane bias index base: j = k0 + s*16 - hh*16 + 4g + r + jbase
  const int jbase = 127 + 4 * g - wid * 32 - lr;

  // prologue: stage tile 0
  gload_lds16(Kg + ((size_t)(0 + krow) * INNER) * 2 + ksrc, (char*)&Ks[0][0] + t * 16);
  gload_lds16(Vg + ((size_t)vrow * SEQ + 0) * 2 + vsrc,     (char*)&Vs[0][0] + t * 16);
  asm volatile("s_waitcnt vmcnt(0)" ::: "memory");
  __syncthreads();

  for (int k0 = 0; k0 < SEQ; k0 += 32) {
    const int buf = (k0 >> 5) & 1;

    // prefetch next tile into the other buffer
    const int k0n = (k0 + 32 < SEQ) ? (k0 + 32) : 0;
    gload_lds16(Kg + ((size_t)(k0n + krow) * INNER) * 2 + ksrc, (char*)&Ks[buf ^ 1][0] + t * 16);
    gload_lds16(Vg + ((size_t)vrow * SEQ + k0n) * 2 + vsrc,     (char*)&Vs[buf ^ 1][0] + t * 16);

    // ---- K and V fragments from LDS (V early: latency hides under QK MFMA)
    const char* kb_ = (const char*)&Ks[buf][0];
    f16x8 kf[2][2];
#pragma unroll
    for (int s = 0; s < 2; ++s)
#pragma unroll
      for (int half = 0; half < 2; ++half)
        kf[s][half] = *(const f16x8*)(kb_ + (s * 16 + lr) * 128 + ((half * 64 + g * 16) ^ ((lr & 7) << 4)));

    const char* vb_ = (const char*)&Vs[buf][0];
    f16x4 vt[2][4];
#pragma unroll
    for (int s = 0; s < 2; ++s)
#pragma unroll
      for (int dn = 0; dn < 4; ++dn)
        vt[s][dn] = *(const f16x4*)(vb_ + (dn * 16 + lr) * 64 + ((s * 32 + g * 8) ^ ((lr & 3) << 4)));

    float4 mb[2];
    mb[0] = *(const float4*)&mbL[k0 + 4 * g];
    mb[1] = *(const float4*)&mbL[k0 + 16 + 4 * g];

    // ---- QK^T with bias+mask as C-operand
    f32x4 sg[2][2];  // [hh][s]
#pragma unroll
    for (int hh = 0; hh < 2; ++hh)
#pragma unroll
      for (int s = 0; s < 2; ++s) {
        const int jA = k0 + s * 16 + jbase - hh * 16;
        f32x4 z;
#pragma unroll
        for (int r = 0; r < 4; ++r)
          z[r] = biasT[jA + r] + ((const float*)&mb[s])[r];
        z = __builtin_amdgcn_mfma_f32_16x16x32_f16(kf[s][0], qa[hh][0], z, 0, 0, 0);
        z = __builtin_amdgcn_mfma_f32_16x16x32_f16(kf[s][1], qa[hh][1], z, 0, 0, 0);
        sg[hh][s] = z;
      }

    // ---- lane-local defer-max: no cross-lane ops unless triggered
    float mxA = fmaxf(fmaxf(fmaxf(sg[0][0][0], sg[0][0][1]), fmaxf(sg[0][0][2], sg[0][0][3])),
                      fmaxf(fmaxf(sg[0][1][0], sg[0][1][1]), fmaxf(sg[0][1][2], sg[0][1][3])));
    float mxB = fmaxf(fmaxf(fmaxf(sg[1][0][0], sg[1][0][1]), fmaxf(sg[1][0][2], sg[1][0][3])),
                      fmaxf(fmaxf(sg[1][1][0], sg[1][1][1]), fmaxf(sg[1][1][2], sg[1][1][3])));

    if (__any((mxA > mrun[0] + 11.5415603f) || (mxB > mrun[1] + 11.5415603f))) {
      // full per-row reduce (lanes lr, lr^16, lr^32, lr^48 share a row)
      mxA = fmaxf(mxA, __shfl_xor(mxA, 16));
      mxB = fmaxf(mxB, __shfl_xor(mxB, 16));
      mxA = fmaxf(mxA, __shfl_xor(mxA, 32));
      mxB = fmaxf(mxB, __shfl_xor(mxB, 32));
      const float mnA = fmaxf(mrun[0], mxA), mnB = fmaxf(mrun[1], mxB);
      const float aA = __builtin_amdgcn_exp2f(mrun[0] - mnA);
      const float aB = __builtin_amdgcn_exp2f(mrun[1] - mnB);
      lsum[0] *= aA; lsum[1] *= aB;
#pragma unroll
      for (int dn = 0; dn < 4; ++dn)
#pragma unroll
        for (int r = 0; r < 4; ++r) { o[0][dn][r] *= aA; o[1][dn][r] *= aB; }
      mrun[0] = mnA; mrun[1] = mnB;
    }

    f16x4 pfA[2], pfB[2];
#pragma unroll
    for (int s = 0; s < 2; ++s)
#pragma unroll
      for (int r = 0; r < 4; ++r) {
        const float pA = __builtin_amdgcn_exp2f(sg[0][s][r] - mrun[0]);
        const float pB = __builtin_amdgcn_exp2f(sg[1][s][r] - mrun[1]);
        lsum[0] += pA; lsum[1] += pB;
        pfA[s][r] = (f16)pA; pfB[s][r] = (f16)pB;
      }

#pragma unroll
    for (int s = 0; s < 2; ++s)
#pragma unroll
      for (int dn = 0; dn < 4; ++dn) {
        o[0][dn] = __builtin_amdgcn_mfma_f32_16x16x16f16(vt[s][dn], pfA[s], o[0][dn], 0, 0, 0);
        o[1][dn] = __builtin_amdgcn_mfma_f32_16x16x16f16(vt[s][dn], pfB[s], o[1][dn], 0, 0, 0);
      }

    asm volatile("s_waitcnt vmcnt(0)" ::: "memory");  // next tile staged
    __syncthreads();
  }

  // epilogue: reduce the per-lane partial sums across the 4 g-groups of each row
  lsum[0] += __shfl_xor(lsum[0], 16);
  lsum[1] += __shfl_xor(lsum[1], 16);
  lsum[0] += __shfl_xor(lsum[0], 32);
  lsum[1] += __shfl_xor(lsum[1], 32);

  const float invA = 1.0f / lsum[0], invB = 1.0f / lsum[1];
#pragma unroll
  for (int dn = 0; dn < 4; ++dn) {
    f16x4 wA, wB;
#pragma unroll
    for (int r = 0; r < 4; ++r) {
      wA[r] = (f16)(o[0][dn][r] * invA);
      wB[r] = (f16)(o[1][dn][r] * invB);
    }
    *(f16x4*)&ctx[(size_t)(b * SEQ + qw + lr) * INNER + h * 64 + dn * 16 + 4 * g] = wA;
    *(f16x4*)&ctx[(size_t)(b * SEQ + qw + 16 + lr) * INNER + h * 64 + dn * 16 + 4 * g] = wB;
  }
}

// ----------------------------------------------------------------- launch
extern "C" void kernel_launch(void* const* d_in, const int* in_sizes, int n_in,
                              void* d_out, int out_size, void* d_ws, size_t ws_size,
                              hipStream_t stream) {
  const float* hs   = (const float*)d_in[0];
  const float* mask = (const float*)d_in[2];
  const float* wq   = (const float*)d_in[3];
  const float* wk   = (const float*)d_in[4];
  const float* wv   = (const float*)d_in[5];
  const float* wo   = (const float*)d_in[6];
  const float* relb = (const float*)d_in[7];

  char* ws = (char*)d_ws;
  const size_t SZ16 = (size_t)MTOT * INNER * 2;      // 16 MiB
  const size_t WSZ  = (size_t)INNER * D_MODEL * 2;   // 2 MiB
  f16* hs16 = (f16*)(ws);                            // reused as ctx16 after QKV
  f16* q16  = (f16*)(ws + SZ16);
  f16* k16  = (f16*)(ws + 2 * SZ16);
  f16* vt16 = (f16*)(ws + 3 * SZ16);                 // V transposed [bh][d][s]
  f16* wq16 = (f16*)(ws + 4 * SZ16);
  f16* wk16 = (f16*)(ws + 4 * SZ16 + WSZ);
  f16* wv16 = (f16*)(ws + 4 * SZ16 + 2 * WSZ);
  f16* wo16 = (f16*)(ws + 4 * SZ16 + 3 * WSZ);
  float* biasG = (float*)(ws + 4 * SZ16 + 4 * WSZ);  // 16*4352*4 = 278,528 B

  // wq pre-scaled by log2(e): QK^T scores land in the log2 domain.
  k_cvt<<<(MTOT * INNER / 4 + 255) / 256, 256, 0, stream>>>(hs, hs16, MTOT * INNER / 4, 1.0f);
  k_cvt<<<(INNER * D_MODEL / 4 + 255) / 256, 256, 0, stream>>>(wq, wq16, INNER * D_MODEL / 4, LOG2E);
  k_cvt<<<(INNER * D_MODEL / 4 + 255) / 256, 256, 0, stream>>>(wk, wk16, INNER * D_MODEL / 4, 1.0f);
  k_cvt<<<(INNER * D_MODEL / 4 + 255) / 256, 256, 0, stream>>>(wv, wv16, INNER * D_MODEL / 4, 1.0f);
  k_cvt<<<(INNER * D_MODEL / 4 + 255) / 256, 256, 0, stream>>>(wo, wo16, INNER * D_MODEL / 4, 1.0f);

  k_bias<<<dim3(BSTRIDE / 256, N_HEADS), 256, 0, stream>>>(relb, biasG);

  k_gemm_qkv<<<dim3(INNER / 128, MTOT / 128, 3), 256, 0, stream>>>(
      hs16, wq16, wk16, wv16, q16, k16, vt16);

  k_attn<<<dim3(1024), 256, 0, stream>>>(
      q16, k16, vt16, biasG, mask, hs16);

  k_gemm_out<<<dim3(D_MODEL / 128, MTOT / 128), 256, 0, stream>>>(
      hs16, wo16, (float*)d_out);
}

// Round 10
// 255.128 us; speedup vs baseline: 3.0364x; 1.1659x over previous
//
#include <hip/hip_runtime.h>
#include <cstdint>
#include <cstddef>

#define D_MODEL 1024
#define N_HEADS 16
#define INNER   1024
#define NBATCH  4
#define SEQ     2048
#define MTOT    (NBATCH * SEQ)   // 8192
#define LOG2E   1.44269504088896f
#define BSTRIDE 4352             // biasG per-head stride
#define MASKC   1442.695041f

typedef _Float16 f16;
typedef __attribute__((ext_vector_type(8))) _Float16 f16x8;
typedef __attribute__((ext_vector_type(4))) _Float16 f16x4;
typedef __attribute__((ext_vector_type(2))) _Float16 f16x2;
typedef __attribute__((ext_vector_type(2))) __fp16   h16x2;
typedef __attribute__((ext_vector_type(4))) float    f32x4;

// packed f32->f16 convert (RTZ) and dot2-accumulate shims (bit-cast between
// clang's __fp16 vectors and our _Float16 vectors; identical layout)
__device__ __forceinline__ f16x2 cvtpk(float x, float y) {
#if __has_builtin(__builtin_amdgcn_cvt_pkrtz)
  h16x2 r = __builtin_amdgcn_cvt_pkrtz(x, y);
  return __builtin_bit_cast(f16x2, r);
#else
  f16x2 r; r[0] = (f16)x; r[1] = (f16)y; return r;
#endif
}
__device__ __forceinline__ float dot2acc(f16x2 p, float acc) {
#if __has_builtin(__builtin_amdgcn_fdot2)
  h16x2 a = __builtin_bit_cast(h16x2, p);
  h16x2 one; one[0] = (__fp16)1.0f; one[1] = (__fp16)1.0f;
  return __builtin_amdgcn_fdot2(a, one, acc, false);
#else
  return acc + (float)p[0] + (float)p[1];
#endif
}

// ---------------------------------------------------------------- f32 -> f16 (with scale)
__global__ void k_cvt(const float* __restrict__ src, f16* __restrict__ dst, int n4, float scale) {
  int i = blockIdx.x * 256 + threadIdx.x;
  if (i < n4) {
    const float4 v = reinterpret_cast<const float4*>(src)[i];
    f16x4 h;
    h[0] = (f16)(v.x * scale); h[1] = (f16)(v.y * scale);
    h[2] = (f16)(v.z * scale); h[3] = (f16)(v.w * scale);
    reinterpret_cast<f16x4*>(dst)[i] = h;
  }
}

// ------------------------------------------------- T5 relative bias, 1-D delta table
// positions = arange(B*S) -> rel = k - q for every batch.
// biasG[h][2048+d] = relb[bucket(d)][h]*LOG2E - MASKC   (mask folded via fma later)
__global__ void k_bias(const float* __restrict__ relb, float* __restrict__ biasG) {
  const int i = blockIdx.x * 256 + threadIdx.x;  // 0..4351
  const int h = blockIdx.y;
  const int d = i - 2048;
  const int sgn = d > 0 ? 16 : 0;
  const int a = d < 0 ? -d : d;
  int bucket;
  if (a < 8) {
    bucket = a;
  } else {
    float t = logf((float)a / 8.0f);
    t = t / 2.772588722239781f;   // ln(16)
    t = t * 8.0f;
    int lg = 8 + (int)t;
    bucket = lg < 15 ? lg : 15;
  }
  biasG[h * BSTRIDE + i] = relb[(sgn + bucket) * N_HEADS + h] * LOG2E - MASKC;
}

// ------------------------------------------------- async global->LDS (16B)
__device__ __forceinline__ void gload_lds16(const void* g, void* l) {
  __builtin_amdgcn_global_load_lds(
      (const __attribute__((address_space(1))) unsigned int*)g,
      (__attribute__((address_space(3))) unsigned int*)l,
      16, 0, 0);
}

// ------------------------------------------------- C = A * W^T  (f16 in, K=1024)
template <int MODE>
__device__ __forceinline__ void gemm_body(const f16* __restrict__ A,
                                          const f16* __restrict__ W,
                                          void* __restrict__ Cp) {
  __shared__ __align__(16) f16 As[128 * 64];
  __shared__ __align__(16) f16 Bs[128 * 64];
  const int t = threadIdx.x;
  const int lane = t & 63;
  const int wid = t >> 6;
  const int wr = wid >> 1;
  const int wc = wid & 1;
  const int g = lane >> 4;
  const int lr = lane & 15;
  const int m0 = blockIdx.y * 128;
  const int n0 = blockIdx.x * 128;

  f32x4 acc[4][4] = {};
  const char* Ab = (const char*)A;
  const char* Wb = (const char*)W;

  for (int kt = 0; kt < D_MODEL / 64; ++kt) {
    const int k0 = kt * 64;
    __syncthreads();
#pragma unroll
    for (int i = 0; i < 4; ++i) {
      const int idx = i * 256 + t;
      const int row = idx >> 3;
      const int cb  = (idx & 7) * 16;
      gload_lds16(Ab + ((size_t)(m0 + row) * D_MODEL + k0) * 2 + cb, (char*)As + idx * 16);
      gload_lds16(Wb + ((size_t)(n0 + row) * D_MODEL + k0) * 2 + cb, (char*)Bs + idx * 16);
    }
    asm volatile("s_waitcnt vmcnt(0)" ::: "memory");
    __syncthreads();

    f16x8 af[4][2], bf[4][2];
#pragma unroll
    for (int mi = 0; mi < 4; ++mi)
#pragma unroll
      for (int kk = 0; kk < 2; ++kk)
        af[mi][kk] = *(const f16x8*)&As[(wr * 64 + mi * 16 + lr) * 64 + kk * 32 + g * 8];
#pragma unroll
    for (int ni = 0; ni < 4; ++ni)
#pragma unroll
      for (int kk = 0; kk < 2; ++kk)
        bf[ni][kk] = *(const f16x8*)&Bs[(wc * 64 + ni * 16 + lr) * 64 + kk * 32 + g * 8];
#pragma unroll
    for (int kk = 0; kk < 2; ++kk)
#pragma unroll
      for (int mi = 0; mi < 4; ++mi)
#pragma unroll
        for (int ni = 0; ni < 4; ++ni)
          acc[mi][ni] = __builtin_amdgcn_mfma_f32_16x16x32_f16(af[mi][kk], bf[ni][kk], acc[mi][ni], 0, 0, 0);
  }

#pragma unroll
  for (int mi = 0; mi < 4; ++mi)
#pragma unroll
    for (int ni = 0; ni < 4; ++ni) {
      const int n = n0 + wc * 64 + ni * 16 + lr;
      if (MODE == 2) {
        const int mbase = m0 + wr * 64 + mi * 16 + g * 4;
        const int b2 = mbase >> 11, s2 = mbase & (SEQ - 1);
        const int h2 = n >> 6, d2 = n & 63;
        f16x4 w;
#pragma unroll
        for (int r = 0; r < 4; ++r) w[r] = (f16)acc[mi][ni][r];
        *(f16x4*)((f16*)Cp + ((size_t)((b2 * 16 + h2) * 64 + d2) * SEQ + s2)) = w;
      } else {
#pragma unroll
        for (int r = 0; r < 4; ++r) {
          const int m = m0 + wr * 64 + mi * 16 + g * 4 + r;
          if (MODE == 1)
            ((float*)Cp)[(size_t)m * INNER + n] = acc[mi][ni][r];
          else
            ((f16*)Cp)[(size_t)m * INNER + n] = (f16)acc[mi][ni][r];
        }
      }
    }
}

__global__ __launch_bounds__(256) void k_gemm_qkv(
    const f16* __restrict__ A,
    const f16* __restrict__ Wq, const f16* __restrict__ Wk, const f16* __restrict__ Wv,
    f16* __restrict__ Cq, f16* __restrict__ Ck, f16* __restrict__ Vt) {
  if (blockIdx.z == 0)      gemm_body<0>(A, Wq, Cq);
  else if (blockIdx.z == 1) gemm_body<0>(A, Wk, Ck);
  else                      gemm_body<2>(A, Wv, Vt);
}

__global__ __launch_bounds__(256) void k_gemm_out(
    const f16* __restrict__ A, const f16* __restrict__ W, float* __restrict__ C) {
  gemm_body<1>(A, W, C);
}

// ------------------------------------------------- flash attention
// Block = 4 waves, one (b,h), 128 q-rows; wave = 32 q.  KVBLK=32, unrolled x2
// over the LDS double-buffer (buf is a compile-time literal).  All swizzled LDS
// offsets hoisted.  Bias (with mask constant pre-baked) enters the QK MFMA as
// C-operand via fma(mask, MASKC, biasT).  Packed f32->f16 cvt + dot2 lsum.
__global__ __launch_bounds__(256, 4) void k_attn(
    const f16* __restrict__ Q, const f16* __restrict__ K, const f16* __restrict__ Vt,
    const float* __restrict__ biasG, const float* __restrict__ mask,
    f16* __restrict__ ctx) {
  __shared__ __align__(16) float biasT[2176];
  __shared__ __align__(16) f16 Ks[2 * 2048];   // [k][d] swz bits 4-6, 4KB/buf
  __shared__ __align__(16) f16 Vs[2 * 2048];   // [d][k] swz bits 4-5, 4KB/buf

  // XCD-aware remap: all 16 q-chunks of one (b,h) on one XCD.
  const int nb = (int)blockIdx.x;
  const int v = (nb & 7) * 128 + (nb >> 3);
  const int bh = v >> 4, qc = v & 15;
  const int b = bh >> 4, h = bh & 15;

  const int t = threadIdx.x, lane = t & 63, wid = t >> 6;
  const int g = lane >> 4, lr = lane & 15;
  const int qb = qc * 128;

  {
    const float* bgh = biasG + (size_t)h * BSTRIDE + (1921 - qb);
    for (int i = t; i < 2176; i += 256) biasT[i] = bgh[i];
  }

  const char* Kg = (const char*)K + ((size_t)(b * SEQ) * INNER + h * 64) * 2;
  const char* Vg = (const char*)Vt + ((size_t)bh * 64) * SEQ * 2;
  const float* maskB = mask + (size_t)b * SEQ;
  const int krow = t >> 3, kch = t & 7;
  const int ksrc = (kch * 16) ^ ((krow & 7) << 4);
  const int vrow = t >> 2, vch = t & 3;
  const int vsrc = (vch * 16) ^ ((vrow & 3) << 4);

  const int qw = qb + wid * 32;

  f16x8 qa[2][2];
#pragma unroll
  for (int hh = 0; hh < 2; ++hh)
#pragma unroll
    for (int kk = 0; kk < 2; ++kk)
      qa[hh][kk] = *(const f16x8*)&Q[(size_t)(b * SEQ + qw + hh * 16 + lr) * INNER + h * 64 + kk * 32 + g * 8];

  // hoisted per-lane LDS byte offsets (loop-invariant)
  int koffs[2][2], voffs[2][4];
#pragma unroll
  for (int s = 0; s < 2; ++s) {
#pragma unroll
    for (int hf = 0; hf < 2; ++hf)
      koffs[s][hf] = (s * 16 + lr) * 128 + ((hf * 64 + g * 16) ^ ((lr & 7) << 4));
#pragma unroll
    for (int dn = 0; dn < 4; ++dn)
      voffs[s][dn] = (dn * 16 + lr) * 64 + ((s * 32 + g * 8) ^ ((lr & 3) << 4));
  }

  f32x4 o[2][4] = {};
  float mrun[2] = {-__builtin_inff(), -__builtin_inff()};
  float lsum[2] = {0.0f, 0.0f};
  const int jbase = 127 + 4 * g - wid * 32 - lr;

  // prologue: stage tile 0 into buf 0
  gload_lds16(Kg + ((size_t)krow * INNER) * 2 + ksrc, (char*)Ks + t * 16);
  gload_lds16(Vg + ((size_t)vrow * SEQ) * 2 + vsrc,   (char*)Vs + t * 16);
  asm volatile("s_waitcnt vmcnt(0)" ::: "memory");
  __syncthreads();

#define ATTN_ITER(BUF, K0)                                                     \
  {                                                                            \
    const float4 mk0 = *(const float4*)(maskB + (K0) + 4 * g);                 \
    const float4 mk1 = *(const float4*)(maskB + (K0) + 16 + 4 * g);            \
    const int k0n_ = ((K0) + 32 < SEQ) ? (K0) + 32 : 0;                        \
    gload_lds16(Kg + ((size_t)(k0n_ + krow) * INNER) * 2 + ksrc,               \
                (char*)Ks + ((BUF) ^ 1) * 4096 + t * 16);                      \
    gload_lds16(Vg + ((size_t)vrow * SEQ + k0n_) * 2 + vsrc,                   \
                (char*)Vs + ((BUF) ^ 1) * 4096 + t * 16);                      \
    f16x8 kf[2][2];                                                            \
    _Pragma("unroll") for (int s = 0; s < 2; ++s)                              \
      _Pragma("unroll") for (int hf = 0; hf < 2; ++hf)                         \
        kf[s][hf] = *(const f16x8*)((const char*)Ks + (BUF) * 4096 + koffs[s][hf]); \
    f16x4 vf[2][4];                                                            \
    _Pragma("unroll") for (int s = 0; s < 2; ++s)                              \
      _Pragma("unroll") for (int dn = 0; dn < 4; ++dn)                         \
        vf[s][dn] = *(const f16x4*)((const char*)Vs + (BUF) * 4096 + voffs[s][dn]); \
    f32x4 sg[2][2];                                                            \
    _Pragma("unroll") for (int hh = 0; hh < 2; ++hh)                           \
      _Pragma("unroll") for (int s = 0; s < 2; ++s) {                          \
        const int jA = (K0) + s * 16 + jbase - hh * 16;                        \
        const float* mkp = (s == 0) ? (const float*)&mk0 : (const float*)&mk1; \
        f32x4 z;                                                               \
        _Pragma("unroll") for (int r = 0; r < 4; ++r)                          \
          z[r] = fmaf(mkp[r], MASKC, biasT[jA + r]);                           \
        z = __builtin_amdgcn_mfma_f32_16x16x32_f16(kf[s][0], qa[hh][0], z, 0, 0, 0); \
        z = __builtin_amdgcn_mfma_f32_16x16x32_f16(kf[s][1], qa[hh][1], z, 0, 0, 0); \
        sg[hh][s] = z;                                                         \
      }                                                                        \
    float mxA = fmaxf(fmaxf(fmaxf(sg[0][0][0], sg[0][0][1]), fmaxf(sg[0][0][2], sg[0][0][3])), \
                      fmaxf(fmaxf(sg[0][1][0], sg[0][1][1]), fmaxf(sg[0][1][2], sg[0][1][3]))); \
    float mxB = fmaxf(fmaxf(fmaxf(sg[1][0][0], sg[1][0][1]), fmaxf(sg[1][0][2], sg[1][0][3])), \
                      fmaxf(fmaxf(sg[1][1][0], sg[1][1][1]), fmaxf(sg[1][1][2], sg[1][1][3]))); \
    if (__any((mxA > mrun[0] + 11.5415603f) || (mxB > mrun[1] + 11.5415603f))) { \
      mxA = fmaxf(mxA, __shfl_xor(mxA, 16));                                   \
      mxB = fmaxf(mxB, __shfl_xor(mxB, 16));                                   \
      mxA = fmaxf(mxA, __shfl_xor(mxA, 32));                                   \
      mxB = fmaxf(mxB, __shfl_xor(mxB, 32));                                   \
      const float mnA = fmaxf(mrun[0], mxA), mnB = fmaxf(mrun[1], mxB);        \
      const float aA = __builtin_amdgcn_exp2f(mrun[0] - mnA);                  \
      const float aB = __builtin_amdgcn_exp2f(mrun[1] - mnB);                  \
      lsum[0] *= aA; lsum[1] *= aB;                                            \
      _Pragma("unroll") for (int dn = 0; dn < 4; ++dn)                         \
        _Pragma("unroll") for (int r = 0; r < 4; ++r) {                        \
          o[0][dn][r] *= aA; o[1][dn][r] *= aB;                                \
        }                                                                      \
      mrun[0] = mnA; mrun[1] = mnB;                                            \
    }                                                                          \
    f16x4 pfA[2], pfB[2];                                                      \
    _Pragma("unroll") for (int s = 0; s < 2; ++s) {                            \
      float eA[4], eB[4];                                                      \
      _Pragma("unroll") for (int r = 0; r < 4; ++r) {                          \
        eA[r] = __builtin_amdgcn_exp2f(sg[0][s][r] - mrun[0]);                 \
        eB[r] = __builtin_amdgcn_exp2f(sg[1][s][r] - mrun[1]);                 \
      }                                                                        \
      const f16x2 a0 = cvtpk(eA[0], eA[1]), a1 = cvtpk(eA[2], eA[3]);          \
      const f16x2 b0 = cvtpk(eB[0], eB[1]), b1 = cvtpk(eB[2], eB[3]);          \
      lsum[0] = dot2acc(a0, lsum[0]); lsum[0] = dot2acc(a1, lsum[0]);          \
      lsum[1] = dot2acc(b0, lsum[1]); lsum[1] = dot2acc(b1, lsum[1]);          \
      pfA[s][0] = a0[0]; pfA[s][1] = a0[1]; pfA[s][2] = a1[0]; pfA[s][3] = a1[1]; \
      pfB[s][0] = b0[0]; pfB[s][1] = b0[1]; pfB[s][2] = b1[0]; pfB[s][3] = b1[1]; \
    }                                                                          \
    _Pragma("unroll") for (int s = 0; s < 2; ++s)                              \
      _Pragma("unroll") for (int dn = 0; dn < 4; ++dn) {                       \
        o[0][dn] = __builtin_amdgcn_mfma_f32_16x16x16f16(vf[s][dn], pfA[s], o[0][dn], 0, 0, 0); \
        o[1][dn] = __builtin_amdgcn_mfma_f32_16x16x16f16(vf[s][dn], pfB[s], o[1][dn], 0, 0, 0); \
      }                                                                        \
    asm volatile("s_waitcnt vmcnt(0)" ::: "memory");                           \
    __syncthreads();                                                           \
  }

  for (int k0 = 0; k0 < SEQ; k0 += 64) {
    ATTN_ITER(0, k0)
    ATTN_ITER(1, k0 + 32)
  }

  // epilogue: reduce per-lane partial sums across the 4 g-groups of each row
  lsum[0] += __shfl_xor(lsum[0], 16);
  lsum[1] += __shfl_xor(lsum[1], 16);
  lsum[0] += __shfl_xor(lsum[0], 32);
  lsum[1] += __shfl_xor(lsum[1], 32);

  const float invA = 1.0f / lsum[0], invB = 1.0f / lsum[1];
#pragma unroll
  for (int dn = 0; dn < 4; ++dn) {
    f16x4 wA, wB;
#pragma unroll
    for (int r = 0; r < 4; ++r) {
      wA[r] = (f16)(o[0][dn][r] * invA);
      wB[r] = (f16)(o[1][dn][r] * invB);
    }
    *(f16x4*)&ctx[(size_t)(b * SEQ + qw + lr) * INNER + h * 64 + dn * 16 + 4 * g] = wA;
    *(f16x4*)&ctx[(size_t)(b * SEQ + qw + 16 + lr) * INNER + h * 64 + dn * 16 + 4 * g] = wB;
  }
}

// ----------------------------------------------------------------- launch
extern "C" void kernel_launch(void* const* d_in, const int* in_sizes, int n_in,
                              void* d_out, int out_size, void* d_ws, size_t ws_size,
                              hipStream_t stream) {
  const float* hs   = (const float*)d_in[0];
  const float* mask = (const float*)d_in[2];
  const float* wq   = (const float*)d_in[3];
  const float* wk   = (const float*)d_in[4];
  const float* wv   = (const float*)d_in[5];
  const float* wo   = (const float*)d_in[6];
  const float* relb = (const float*)d_in[7];

  char* ws = (char*)d_ws;
  const size_t SZ16 = (size_t)MTOT * INNER * 2;      // 16 MiB
  const size_t WSZ  = (size_t)INNER * D_MODEL * 2;   // 2 MiB
  f16* hs16 = (f16*)(ws);                            // reused as ctx16 after QKV
  f16* q16  = (f16*)(ws + SZ16);
  f16* k16  = (f16*)(ws + 2 * SZ16);
  f16* vt16 = (f16*)(ws + 3 * SZ16);                 // V transposed [bh][d][s]
  f16* wq16 = (f16*)(ws + 4 * SZ16);
  f16* wk16 = (f16*)(ws + 4 * SZ16 + WSZ);
  f16* wv16 = (f16*)(ws + 4 * SZ16 + 2 * WSZ);
  f16* wo16 = (f16*)(ws + 4 * SZ16 + 3 * WSZ);
  float* biasG = (float*)(ws + 4 * SZ16 + 4 * WSZ);  // 16*4352*4 B

  // wq pre-scaled by log2(e): QK^T scores land in the log2 domain.
  k_cvt<<<(MTOT * INNER / 4 + 255) / 256, 256, 0, stream>>>(hs, hs16, MTOT * INNER / 4, 1.0f);
  k_cvt<<<(INNER * D_MODEL / 4 + 255) / 256, 256, 0, stream>>>(wq, wq16, INNER * D_MODEL / 4, LOG2E);
  k_cvt<<<(INNER * D_MODEL / 4 + 255) / 256, 256, 0, stream>>>(wk, wk16, INNER * D_MODEL / 4, 1.0f);
  k_cvt<<<(INNER * D_MODEL / 4 + 255) / 256, 256, 0, stream>>>(wv, wv16, INNER * D_MODEL / 4, 1.0f);
  k_cvt<<<(INNER * D_MODEL / 4 + 255) / 256, 256, 0, stream>>>(wo, wo16, INNER * D_MODEL / 4, 1.0f);

  k_bias<<<dim3(BSTRIDE / 256, N_HEADS), 256, 0, stream>>>(relb, biasG);

  k_gemm_qkv<<<dim3(INNER / 128, MTOT / 128, 3), 256, 0, stream>>>(
      hs16, wq16, wk16, wv16, q16, k16, vt16);

  k_attn<<<dim3(1024), 256, 0, stream>>>(
      q16, k16, vt16, biasG, mask, hs16);

  k_gemm_out<<<dim3(D_MODEL / 128, MTOT / 128), 256, 0, stream>>>(
      hs16, wo16, (float*)d_out);
}